// Round 15
// baseline (414.023 us; speedup 1.0000x reference)
//
#include <hip/hip_runtime.h>
#include <hip/hip_fp16.h>
#include <math.h>

#define CDIV(a, b) (((a) + (b) - 1) / (b))
#define SCAN_BS 1024
#define NBUK 512          // dst buckets (dst>>7), 512 >= CDIV(65536,128)
#define ATILE 8192        // edges per Stage-A block

// ---------- float <-> monotone-unsigned encoding for atomicMax on floats ----
__device__ __forceinline__ unsigned encf(float v) {
    unsigned u = __float_as_uint(v);
    return (u & 0x80000000u) ? ~u : (u | 0x80000000u);
}
__device__ __forceinline__ float decf(unsigned k) {
    unsigned u = (k & 0x80000000u) ? (k ^ 0x80000000u) : ~k;
    return __uint_as_float(u);
}

__device__ __forceinline__ float lrelu(float v) {
    return v > 0.f ? v : 0.2f * v;
}

// ---------- typed 4-element store (fp32 or fp16 output) ---------------------
template <typename OT>
__device__ __forceinline__ void store4(OT* p, const float* a);
template <>
__device__ __forceinline__ void store4<float>(float* p, const float* a) {
    *(float4*)p = *(const float4*)a;
}
template <>
__device__ __forceinline__ void store4<__half>(__half* p, const float* a) {
    __half2 p0 = __floats2half2_rn(a[0], a[1]);
    __half2 p1 = __floats2half2_rn(a[2], a[3]);
    uint2 u;
    u.x = *(unsigned*)&p0;
    u.y = *(unsigned*)&p1;
    *(uint2*)p = u;
}

// ---------- naive GEMM fallback (only if shapes are unexpected) -------------
__global__ __launch_bounds__(256) void gemm_kernel(
    const float* __restrict__ X, const float* __restrict__ W,
    float* __restrict__ Y, int M, int K, int Nout) {
    int idx = blockIdx.x * blockDim.x + threadIdx.x;
    if (idx >= M * Nout) return;
    int row = idx / Nout;
    int col = idx - row * Nout;
    const float* xr = X + (size_t)row * K;
    const float* wc = W + col;
    float acc = 0.f;
    for (int k = 0; k < K; k += 4) {
        float4 xv = *(const float4*)(xr + k);
        acc += xv.x * wc[(size_t)(k + 0) * Nout];
        acc += xv.y * wc[(size_t)(k + 1) * Nout];
        acc += xv.z * wc[(size_t)(k + 2) * Nout];
        acc += xv.w * wc[(size_t)(k + 3) * Nout];
    }
    Y[idx] = acc;
}

// ---------- LDS-tiled GEMM (both operands in LDS) + fused attention dots ----
// KB=32 k-tiles; X tile staged in LDS (padded rows) so the inner loop has
// ZERO global loads — X was previously read 32x redundantly through L1.
// ROWS=32 doubles the grid (1563 blocks) vs the old 64-row tile, lifting the
// grid-capped occupancy (was 782 blocks -> ~3/CU -> 14%).
template <int K, int NOUT, int RPT, int H, typename OT>
__global__ __launch_bounds__(256) void gemm_attn(
    const float* __restrict__ X, const float* __restrict__ W,
    const float* __restrict__ asrc, const float* __restrict__ adst,
    OT* __restrict__ Y, float* __restrict__ es, float* __restrict__ ed,
    int M) {
    constexpr int TX = NOUT / 4;
    constexpr int TY = 256 / TX;
    constexpr int ROWS = TY * RPT;
    constexpr int KB = (K > 32) ? 32 : K;
    constexpr int XP = KB + 4;   // padded X row stride (breaks bank aliasing)
    constexpr int C = 32;        // head dim
    constexpr int GP = C / 4;    // threads per (row, head)
    __shared__ float Wl[KB * NOUT];
    __shared__ float Xl[ROWS * XP];
    const int t = threadIdx.x;
    const int tx = t % TX;
    const int ty = t / TX;
    const int row0 = blockIdx.x * ROWS;
    float acc[RPT][4] = {};
    for (int kb = 0; kb < K; kb += KB) {
        constexpr int NLD = KB * NOUT / 4 / 256;
#pragma unroll
        for (int j = 0; j < NLD; ++j) {
            int idx = t + 256 * j;
            ((float4*)Wl)[idx] =
                ((const float4*)(W + (size_t)kb * NOUT))[idx];
        }
        constexpr int XLD = ROWS * KB / 4 / 256;  // = 1 for 32x32
#pragma unroll
        for (int j = 0; j < XLD; ++j) {
            int idx = t + 256 * j;
            int xr = idx / (KB / 4);
            int xc = idx - xr * (KB / 4);
            int gr = row0 + xr;
            gr = gr < M ? gr : (M - 1);
            *(float4*)&Xl[xr * XP + xc * 4] =
                ((const float4*)(X + (size_t)gr * K + kb))[xc];
        }
        __syncthreads();
#pragma unroll
        for (int k4 = 0; k4 < KB / 4; ++k4) {
            float4 xv[RPT];
#pragma unroll
            for (int i = 0; i < RPT; ++i)
                xv[i] = *(const float4*)&Xl[(ty + TY * i) * XP + 4 * k4];
            float4 wv[4];
#pragma unroll
            for (int j = 0; j < 4; ++j)
                wv[j] = *(const float4*)&Wl[(4 * k4 + j) * NOUT + tx * 4];
#pragma unroll
            for (int i = 0; i < RPT; ++i) {
                acc[i][0] += xv[i].x * wv[0].x + xv[i].y * wv[1].x +
                             xv[i].z * wv[2].x + xv[i].w * wv[3].x;
                acc[i][1] += xv[i].x * wv[0].y + xv[i].y * wv[1].y +
                             xv[i].z * wv[2].y + xv[i].w * wv[3].y;
                acc[i][2] += xv[i].x * wv[0].z + xv[i].y * wv[1].z +
                             xv[i].z * wv[2].z + xv[i].w * wv[3].z;
                acc[i][3] += xv[i].x * wv[0].w + xv[i].y * wv[1].w +
                             xv[i].z * wv[2].w + xv[i].w * wv[3].w;
            }
        }
        __syncthreads();
    }
    const int hh = tx / GP;      // head of this thread's 4 cols
    const int q = tx % GP;       // position within head
    float asv[4], adv[4];
#pragma unroll
    for (int j = 0; j < 4; ++j) {
        asv[j] = asrc[hh * C + q * 4 + j];
        adv[j] = adst[hh * C + q * 4 + j];
    }
#pragma unroll
    for (int i = 0; i < RPT; ++i) {
        int r = row0 + ty + TY * i;
        float ps = acc[i][0] * asv[0] + acc[i][1] * asv[1] +
                   acc[i][2] * asv[2] + acc[i][3] * asv[3];
        float pd = acc[i][0] * adv[0] + acc[i][1] * adv[1] +
                   acc[i][2] * adv[2] + acc[i][3] * adv[3];
        ps += __shfl_xor(ps, 1); ps += __shfl_xor(ps, 2); ps += __shfl_xor(ps, 4);
        pd += __shfl_xor(pd, 1); pd += __shfl_xor(pd, 2); pd += __shfl_xor(pd, 4);
        if (r < M) {
            store4<OT>(Y + (size_t)r * NOUT + tx * 4, acc[i]);
            if (q == 0) {
                es[r * H + hh] = ps;
                ed[r * H + hh] = pd;
            }
        }
    }
}

// ---------- attention coefficients (fallback path) --------------------------
__global__ __launch_bounds__(256) void attn_kernel(
    const float* __restrict__ h, const float* __restrict__ a_src,
    const float* __restrict__ a_dst, float* __restrict__ es,
    float* __restrict__ ed, int N, int H, int C) {
    int idx = blockIdx.x * blockDim.x + threadIdx.x;
    if (idx >= N * H) return;
    int n = idx / H;
    int hh = idx - n * H;
    const float* hp = h + (size_t)n * H * C + (size_t)hh * C;
    const float* ap = a_src + hh * C;
    const float* bp = a_dst + hh * C;
    float s = 0.f, d = 0.f;
    for (int c = 0; c < C; c += 4) {
        float4 hv = *(const float4*)(hp + c);
        float4 av = *(const float4*)(ap + c);
        float4 bv = *(const float4*)(bp + c);
        s += hv.x * av.x + hv.y * av.y + hv.z * av.z + hv.w * av.w;
        d += hv.x * bv.x + hv.y * bv.y + hv.z * bv.z + hv.w * bv.w;
    }
    es[idx] = s;
    ed[idx] = d;
}

// ---------- CSR build: degree histogram over REAL edges only ----------------
__global__ __launch_bounds__(256) void deg_kernel(const int* __restrict__ ei,
                                                  int E,
                                                  int* __restrict__ deg) {
    int e = blockIdx.x * blockDim.x + threadIdx.x;
    if (e >= E) return;
    atomicAdd(&deg[ei[E + e]], 1);
}

// ---------- CSR build: 3-kernel exclusive scan of (deg+1) -------------------
__global__ __launch_bounds__(SCAN_BS) void scan1_kernel(
    const int* __restrict__ deg, int* __restrict__ rowptr,
    int* __restrict__ bsum, int N) {
    __shared__ int tmp[SCAN_BS];
    int tid = threadIdx.x;
    int gid = blockIdx.x * SCAN_BS + tid;
    int v = (gid < N) ? (deg[gid] + 1) : 0;  // +1 = reserved self-loop slot
    tmp[tid] = v;
    __syncthreads();
    for (int off = 1; off < SCAN_BS; off <<= 1) {
        int t = (tid >= off) ? tmp[tid - off] : 0;
        __syncthreads();
        tmp[tid] += t;
        __syncthreads();
    }
    if (gid < N) rowptr[gid] = tmp[tid] - v;  // exclusive
    if (tid == SCAN_BS - 1) bsum[blockIdx.x] = tmp[tid];
}

__global__ void scan2_kernel(int* __restrict__ bsum, int nb) {
    if (threadIdx.x == 0 && blockIdx.x == 0) {
        int acc = 0;
        for (int i = 0; i < nb; ++i) {
            int t = bsum[i];
            bsum[i] = acc;
            acc += t;
        }
    }
}

// finalizes rowptr, seeds cursor (= rowptr+1), writes self-loop into slot 0
__global__ __launch_bounds__(SCAN_BS) void scan3_kernel(
    int* __restrict__ rowptr, int* __restrict__ cursor,
    int* __restrict__ csrc, const int* __restrict__ bsum, int N, int total) {
    int gid = blockIdx.x * SCAN_BS + threadIdx.x;
    if (gid < N) {
        int v = rowptr[gid] + bsum[blockIdx.x];
        rowptr[gid] = v;
        cursor[gid] = v + 1;
        csrc[v] = gid;  // self-loop occupies slot 0
    }
    if (gid == 0) rowptr[N] = total;
}

// ---------- Stage A1: per-block bucket histogram (bucket = dst>>7) ----------
__global__ __launch_bounds__(256) void binA1_kernel(
    const int* __restrict__ ei, int E, int* __restrict__ ghist) {
    __shared__ int lh[NBUK];
    int t = threadIdx.x;
    for (int i = t; i < NBUK; i += 256) lh[i] = 0;
    __syncthreads();
    int base = blockIdx.x * ATILE;
#pragma unroll 4
    for (int j = 0; j < ATILE / 256; ++j) {
        int idx = base + t + 256 * j;
        if (idx < E) atomicAdd(&lh[ei[E + idx] >> 7], 1);
    }
    __syncthreads();
    int* gh = ghist + (size_t)blockIdx.x * NBUK;
    for (int i = t; i < NBUK; i += 256) gh[i] = lh[i];
}

// ---------- Stage A2: offsets — single block, one thread per bucket ---------
__global__ __launch_bounds__(NBUK) void binA2_kernel(
    int* __restrict__ ghist, int* __restrict__ bucketptr, int nblk, int E) {
    __shared__ int tot[NBUK];
    int b = threadIdx.x;
    int acc = 0;
    for (int blk = 0; blk < nblk; ++blk) {
        int v = ghist[(size_t)blk * NBUK + b];
        ghist[(size_t)blk * NBUK + b] = acc;
        acc += v;
    }
    tot[b] = acc;
    __syncthreads();
    __shared__ int sc[NBUK];
    sc[b] = tot[b];
    __syncthreads();
    for (int off = 1; off < NBUK; off <<= 1) {
        int v = (b >= off) ? sc[b - off] : 0;
        __syncthreads();
        sc[b] += v;
        __syncthreads();
    }
    int base = sc[b] - tot[b];  // exclusive
    bucketptr[b] = base;
    if (b == NBUK - 1) bucketptr[NBUK] = E;
    __syncthreads();
    for (int blk = 0; blk < nblk; ++blk)
        ghist[(size_t)blk * NBUK + b] += base;
}

// ---------- Stage A3: binned scatter of packed (dst<<16)|src ----------------
__global__ __launch_bounds__(256) void binA3_kernel(
    const int* __restrict__ ei, int E, const int* __restrict__ ghist,
    unsigned* __restrict__ ebuf) {
    __shared__ int lcur[NBUK];
    int t = threadIdx.x;
    const int* gh = ghist + (size_t)blockIdx.x * NBUK;
    for (int i = t; i < NBUK; i += 256) lcur[i] = gh[i];
    __syncthreads();
    int base = blockIdx.x * ATILE;
#pragma unroll 4
    for (int j = 0; j < ATILE / 256; ++j) {
        int idx = base + t + 256 * j;
        if (idx < E) {
            int s = ei[idx];
            int d = ei[E + idx];
            int pos = atomicAdd(&lcur[d >> 7], 1);
            ebuf[pos] = ((unsigned)d << 16) | (unsigned)s;
        }
    }
}

// ---------- Stage B: one block per bucket -> final CSR scatter --------------
__global__ __launch_bounds__(256) void binB_kernel(
    const unsigned* __restrict__ ebuf, const int* __restrict__ bucketptr,
    const int* __restrict__ rowptr, int* __restrict__ csrc, int N) {
    __shared__ int lcur[128];
    int b = blockIdx.x;
    int t = threadIdx.x;
    int n0 = b << 7;
    if (t < 128) {
        int n = n0 + t;
        lcur[t] = (n < N) ? (rowptr[n] + 1) : 0;  // slot 0 = self-loop
    }
    __syncthreads();
    int beg = bucketptr[b], end = bucketptr[b + 1];
    for (int i = beg + t; i < end; i += 256) {
        unsigned e = ebuf[i];
        int d = (int)(e >> 16);
        int s = (int)(e & 0xFFFFu);
        int pos = atomicAdd(&lcur[d - n0], 1);
        csrc[pos] = s;
    }
}

// ---------- CSR build: standalone scatter (fallback path) -------------------
__global__ __launch_bounds__(256) void scatter_kernel(
    const int* __restrict__ ei, int E, int* __restrict__ cursor,
    int* __restrict__ csrc) {
    int e = blockIdx.x * blockDim.x + threadIdx.x;
    if (e >= E) return;
    int s = ei[e];
    int d = ei[E + e];
    int pos = atomicAdd(&cursor[d], 1);
    csrc[pos] = s;
}

// ---------- fused softmax-aggregate + bias + LN + ELU, D=128, H=4 -----------
__global__ __launch_bounds__(256) void aggr_ln128_kernel(
    const int* __restrict__ rowptr, const int* __restrict__ csrc,
    const __half* __restrict__ h, const float* __restrict__ es,
    const float* __restrict__ ed, const float* __restrict__ bias,
    const float* __restrict__ gam, const float* __restrict__ bet,
    float* __restrict__ outp, int N) {
    constexpr int D = 128, H = 4;
    int wave = (blockIdx.x * blockDim.x + threadIdx.x) >> 6;
    int lane = threadIdx.x & 63;
    int grp = lane >> 5;
    int li = lane & 31;
    int d = wave * 2 + grp;
    if (d >= N) return;
    int c = li * 4;          // 4 consecutive channels
    int hh = li >> 3;        // head index
    float edv = ed[d * H + hh];
    float l = 0.f;
    float ax = 0.f, ay = 0.f, az = 0.f, aw = 0.f;
    int k = rowptr[d], end = rowptr[d + 1];
    for (; k + 8 <= end; k += 8) {
        int s[8];
#pragma unroll
        for (int j = 0; j < 8; ++j) s[j] = csrc[k + j];
        float e[8];
#pragma unroll
        for (int j = 0; j < 8; ++j) e[j] = es[s[j] * H + hh];
        uint2 u[8];
#pragma unroll
        for (int j = 0; j < 8; ++j)
            u[j] = *(const uint2*)(h + (size_t)s[j] * D + c);
#pragma unroll
        for (int j = 0; j < 8; ++j) {
            float w = __expf(lrelu(e[j] + edv));
            float2 f0 = __half22float2(*(__half2*)&u[j].x);
            float2 f1 = __half22float2(*(__half2*)&u[j].y);
            l += w;
            ax += w * f0.x; ay += w * f0.y; az += w * f1.x; aw += w * f1.y;
        }
    }
    for (; k + 4 <= end; k += 4) {
        int s[4];
#pragma unroll
        for (int j = 0; j < 4; ++j) s[j] = csrc[k + j];
        float e[4];
#pragma unroll
        for (int j = 0; j < 4; ++j) e[j] = es[s[j] * H + hh];
        uint2 u[4];
#pragma unroll
        for (int j = 0; j < 4; ++j)
            u[j] = *(const uint2*)(h + (size_t)s[j] * D + c);
#pragma unroll
        for (int j = 0; j < 4; ++j) {
            float w = __expf(lrelu(e[j] + edv));
            float2 f0 = __half22float2(*(__half2*)&u[j].x);
            float2 f1 = __half22float2(*(__half2*)&u[j].y);
            l += w;
            ax += w * f0.x; ay += w * f0.y; az += w * f1.x; aw += w * f1.y;
        }
    }
    for (; k < end; ++k) {
        int s = csrc[k];
        float w = __expf(lrelu(es[s * H + hh] + edv));
        uint2 u = *(const uint2*)(h + (size_t)s * D + c);
        float2 f0 = __half22float2(*(__half2*)&u.x);
        float2 f1 = __half22float2(*(__half2*)&u.y);
        l += w;
        ax += w * f0.x; ay += w * f0.y; az += w * f1.x; aw += w * f1.y;
    }
    float rl = 1.f / (l + 1e-16f);
    float4 b4 = *(const float4*)(bias + c);
    float v0 = ax * rl + b4.x;
    float v1 = ay * rl + b4.y;
    float v2 = az * rl + b4.z;
    float v3 = aw * rl + b4.w;
    float s = v0 + v1 + v2 + v3;
    float ss = v0 * v0 + v1 * v1 + v2 * v2 + v3 * v3;
    for (int off = 16; off; off >>= 1) {
        s += __shfl_xor(s, off);
        ss += __shfl_xor(ss, off);
    }
    float mean = s / D;
    float var = ss / D - mean * mean;
    float rstd = rsqrtf(var + 1e-5f);
    float4 g4 = *(const float4*)(gam + c);
    float4 t4 = *(const float4*)(bet + c);
    float4 o;
    o.x = (v0 - mean) * rstd * g4.x + t4.x;
    o.y = (v1 - mean) * rstd * g4.y + t4.y;
    o.z = (v2 - mean) * rstd * g4.z + t4.z;
    o.w = (v3 - mean) * rstd * g4.w + t4.w;
    o.x = o.x > 0.f ? o.x : expm1f(o.x);
    o.y = o.y > 0.f ? o.y : expm1f(o.y);
    o.z = o.z > 0.f ? o.z : expm1f(o.z);
    o.w = o.w > 0.f ? o.w : expm1f(o.w);
    *(float4*)(outp + (size_t)d * D + c) = o;
}

// ---------- layer 3: aggregate (D=32) + bias + LN + ELU + pool --------------
__global__ __launch_bounds__(256) void aggr_ln32_pool_kernel(
    const int* __restrict__ rowptr, const int* __restrict__ csrc,
    const __half* __restrict__ h, const float* __restrict__ es,
    const float* __restrict__ ed, const float* __restrict__ bias,
    const float* __restrict__ gam, const float* __restrict__ bet,
    const int* __restrict__ batch, float* __restrict__ psum,
    unsigned* __restrict__ pmax, float* __restrict__ cnt, int N) {
    constexpr int D = 32;
    __shared__ float lsum[2][32];
    __shared__ unsigned lmax[2][32];
    __shared__ float lcnt[2];
    __shared__ int g0s;
    int tid = threadIdx.x;
    int wave = (blockIdx.x * blockDim.x + tid) >> 6;
    int lane = tid & 63;
    int half = lane >> 5;
    int c = lane & 31;
    int d = wave * 2 + half;
    int dbase = blockIdx.x * 8;  // first node of this block
    if (tid < 64) {
        lsum[tid >> 5][tid & 31] = 0.f;
        lmax[tid >> 5][tid & 31] = 0u;
    }
    if (tid < 2) lcnt[tid] = 0.f;
    if (tid == 0) g0s = batch[dbase < N ? dbase : (N - 1)];
    __syncthreads();
    int g0 = g0s;
    bool active = d < N;
    if (active) {
        float edv = ed[d];
        float l = 0.f, acc = 0.f;
        int k = rowptr[d], end = rowptr[d + 1];
        for (; k + 8 <= end; k += 8) {
            int s[8];
#pragma unroll
            for (int j = 0; j < 8; ++j) s[j] = csrc[k + j];
            float e[8];
#pragma unroll
            for (int j = 0; j < 8; ++j) e[j] = es[s[j]];
            float hv[8];
#pragma unroll
            for (int j = 0; j < 8; ++j)
                hv[j] = __half2float(h[(size_t)s[j] * D + c]);
#pragma unroll
            for (int j = 0; j < 8; ++j) {
                float w = __expf(lrelu(e[j] + edv));
                l += w;
                acc += w * hv[j];
            }
        }
        for (; k + 4 <= end; k += 4) {
            int s[4];
#pragma unroll
            for (int j = 0; j < 4; ++j) s[j] = csrc[k + j];
            float e[4];
#pragma unroll
            for (int j = 0; j < 4; ++j) e[j] = es[s[j]];
            float hv[4];
#pragma unroll
            for (int j = 0; j < 4; ++j)
                hv[j] = __half2float(h[(size_t)s[j] * D + c]);
#pragma unroll
            for (int j = 0; j < 4; ++j) {
                float w = __expf(lrelu(e[j] + edv));
                l += w;
                acc += w * hv[j];
            }
        }
        for (; k < end; ++k) {
            int s = csrc[k];
            float w = __expf(lrelu(es[s] + edv));
            l += w;
            acc += w * __half2float(h[(size_t)s * D + c]);
        }
        float v = acc / (l + 1e-16f) + bias[c];
        float sm = v, ss = v * v;
        for (int off = 16; off; off >>= 1) {
            sm += __shfl_xor(sm, off);
            ss += __shfl_xor(ss, off);
        }
        float mean = sm / D;
        float var = ss / D - mean * mean;
        float rstd = rsqrtf(var + 1e-5f);
        float o = (v - mean) * rstd * gam[c] + bet[c];
        o = o > 0.f ? o : expm1f(o);
        int g = batch[d];
        int goff = g - g0;
        if (goff >= 0 && goff < 2) {
            atomicAdd(&lsum[goff][c], o);
            atomicMax(&lmax[goff][c], encf(o));
            if (c == 0) atomicAdd(&lcnt[goff], 1.0f);
        } else {
            atomicAdd(&psum[g * D + c], o);
            atomicMax(&pmax[g * D + c], encf(o));
            if (c == 0) atomicAdd(&cnt[g], 1.0f);
        }
    }
    __syncthreads();
    if (tid < 64) {
        int go = tid >> 5, cc = tid & 31;
        unsigned m = lmax[go][cc];
        if (m != 0u) {
            int gg = g0 + go;
            atomicAdd(&psum[gg * D + cc], lsum[go][cc]);
            atomicMax(&pmax[gg * D + cc], m);
            if (cc == 0) atomicAdd(&cnt[gg], lcnt[go]);
        }
    }
}

// ---------- fallback aggregation (online softmax, generic shapes) -----------
__global__ __launch_bounds__(256) void aggr_csr_kernel(
    const int* __restrict__ rowptr, const int* __restrict__ csrc,
    const float* __restrict__ h, const float* __restrict__ es,
    const float* __restrict__ ed, float* __restrict__ outp, int N, int H,
    int C) {
    int D = H * C;
    int wave = (blockIdx.x * blockDim.x + threadIdx.x) >> 6;
    int lane = threadIdx.x & 63;
    if (wave >= N) return;
    int d = wave;
    int c0 = lane, c1 = lane + 64;
    bool a0 = c0 < D, a1 = c1 < D;
    int h0 = a0 ? c0 / C : 0;
    int h1 = a1 ? c1 / C : 0;
    float edv0 = a0 ? ed[d * H + h0] : 0.f;
    float edv1 = a1 ? ed[d * H + h1] : 0.f;
    float m0 = -INFINITY, m1 = -INFINITY;
    float l0 = 0.f, l1 = 0.f, acc0 = 0.f, acc1 = 0.f;
    int beg = rowptr[d], end = rowptr[d + 1];
    for (int k = beg; k < end; ++k) {
        int s = csrc[k];
        const float* hp = h + (size_t)s * D;
        if (a0) {
            float v = lrelu(es[s * H + h0] + edv0);
            float nm = fmaxf(m0, v);
            float sc = __expf(m0 - nm);
            float w = __expf(v - nm);
            l0 = l0 * sc + w;
            acc0 = acc0 * sc + w * hp[c0];
            m0 = nm;
        }
        if (a1) {
            float v = lrelu(es[s * H + h1] + edv1);
            float nm = fmaxf(m1, v);
            float sc = __expf(m1 - nm);
            float w = __expf(v - nm);
            l1 = l1 * sc + w;
            acc1 = acc1 * sc + w * hp[c1];
            m1 = nm;
        }
    }
    if (a0) outp[(size_t)d * D + c0] = acc0 / (l0 + 1e-16f);
    if (a1) outp[(size_t)d * D + c1] = acc1 / (l1 + 1e-16f);
}

// ---------- bias + LayerNorm + ELU (fallback path) --------------------------
__global__ __launch_bounds__(64) void ln_elu_kernel(
    const float* __restrict__ in, const float* __restrict__ bias,
    const float* __restrict__ gam, const float* __restrict__ bet,
    float* __restrict__ outp, int D) {
    int n = blockIdx.x;
    int lane = threadIdx.x;  // blockDim = 64
    int c0 = lane, c1 = lane + 64;
    bool a0 = c0 < D, a1 = c1 < D;
    float v0 = 0.f, v1 = 0.f;
    if (a0) v0 = in[(size_t)n * D + c0] + bias[c0];
    if (a1) v1 = in[(size_t)n * D + c1] + bias[c1];
    float s = v0 + v1;
    float ss = v0 * v0 + v1 * v1;
    for (int off = 32; off; off >>= 1) {
        s += __shfl_xor(s, off);
        ss += __shfl_xor(ss, off);
    }
    float mean = s / D;
    float var = ss / D - mean * mean;
    float rstd = rsqrtf(var + 1e-5f);
    if (a0) {
        float o = (v0 - mean) * rstd * gam[c0] + bet[c0];
        outp[(size_t)n * D + c0] = o > 0.f ? o : expm1f(o);
    }
    if (a1) {
        float o = (v1 - mean) * rstd * gam[c1] + bet[c1];
        outp[(size_t)n * D + c1] = o > 0.f ? o : expm1f(o);
    }
}

// ---------- graph pooling (fallback path) -----------------------------------
__global__ __launch_bounds__(256) void pool_kernel(
    const float* __restrict__ h, const int* __restrict__ batch, int N, int C,
    float* __restrict__ psum, unsigned* __restrict__ pmax,
    float* __restrict__ cnt) {
    int idx = blockIdx.x * blockDim.x + threadIdx.x;
    if (idx >= N * C) return;
    int n = idx / C;
    int c = idx - n * C;
    int g = batch[n];
    float v = h[(size_t)n * C + c];
    atomicAdd(&psum[g * C + c], v);
    atomicMax(&pmax[g * C + c], encf(v));
    if (c == 0) atomicAdd(&cnt[g], 1.0f);
}

// ---------- classifier MLP: one block (1 wave) per graph --------------------
__global__ __launch_bounds__(64) void mlp_kernel(
    const float* __restrict__ psum, const unsigned* __restrict__ pmax,
    const float* __restrict__ cnt, const float* __restrict__ cW1,
    const float* __restrict__ cb1, const float* __restrict__ cW2,
    const float* __restrict__ cb2, const float* __restrict__ cW3,
    const float* __restrict__ cb3, float* __restrict__ outp, int C) {
    __shared__ float f[64];
    __shared__ float t1[32];
    __shared__ float t2[16];
    int g = blockIdx.x;
    int t = threadIdx.x;
    float c = fmaxf(cnt[g], 1.0f);
    if (t < C) {
        f[t] = psum[g * C + t] / c;
    } else if (t < 2 * C) {
        unsigned k = pmax[g * C + (t - C)];
        f[t] = (k == 0u) ? -INFINITY : decf(k);
    }
    __syncthreads();
    if (t < 32) {
        float a = cb1[t];
        for (int i = 0; i < 64; ++i) a += f[i] * cW1[t * 64 + i];
        t1[t] = fmaxf(a, 0.f);
    }
    __syncthreads();
    if (t < 16) {
        float a = cb2[t];
        for (int i = 0; i < 32; ++i) a += t1[i] * cW2[t * 32 + i];
        t2[t] = fmaxf(a, 0.f);
    }
    __syncthreads();
    if (t == 0) {
        float a = cb3[0];
        for (int i = 0; i < 16; ++i) a += t2[i] * cW3[i];
        outp[g] = a;
    }
}

// ---------------------------------------------------------------------------
extern "C" void kernel_launch(void* const* d_in, const int* in_sizes, int n_in,
                              void* d_out, int out_size, void* d_ws,
                              size_t ws_size, hipStream_t stream) {
    const float* x = (const float*)d_in[0];
    const int* ei = (const int*)d_in[1];
    const int* batch = (const int*)d_in[2];
    const float* W1 = (const float*)d_in[4];
    const float* as1 = (const float*)d_in[5];
    const float* ad1 = (const float*)d_in[6];
    const float* b1 = (const float*)d_in[7];
    const float* g1 = (const float*)d_in[8];
    const float* be1 = (const float*)d_in[9];
    const float* W2 = (const float*)d_in[10];
    const float* as2 = (const float*)d_in[11];
    const float* ad2 = (const float*)d_in[12];
    const float* b2 = (const float*)d_in[13];
    const float* g2 = (const float*)d_in[14];
    const float* be2 = (const float*)d_in[15];
    const float* W3 = (const float*)d_in[16];
    const float* as3 = (const float*)d_in[17];
    const float* ad3 = (const float*)d_in[18];
    const float* b3 = (const float*)d_in[19];
    const float* g3 = (const float*)d_in[20];
    const float* be3 = (const float*)d_in[21];
    const float* cW1 = (const float*)d_in[22];
    const float* cb1 = (const float*)d_in[23];
    const float* cW2 = (const float*)d_in[24];
    const float* cb2 = (const float*)d_in[25];
    const float* cW3 = (const float*)d_in[26];
    const float* cb3 = (const float*)d_in[27];

    const int N = in_sizes[2];            // 50000
    const int E = in_sizes[1] / 2;        // 800000
    const int F0 = in_sizes[0] / N;       // 32
    const int Hd = in_sizes[19];          // 32 (b3)
    const int H = in_sizes[5] / Hd;       // 4
    const int D = H * Hd;                 // 128
    const int H3 = in_sizes[17] / Hd;     // 1
    const int G = out_size;               // 512
    const int EN = E + N;
    const bool shapes_ok = (F0 == 32 && Hd == 32 && H == 4 && D == 128 &&
                            H3 == 1 && N <= 65536);

    // -------- workspace carve-out (256B aligned) --------
    char* w = (char*)d_ws;
    size_t off = 0;
    auto carve = [&](size_t bytes) -> void* {
        void* p = w + off;
        off = (off + bytes + 255) & ~(size_t)255;
        return p;
    };
    float* Q = (float*)carve((size_t)N * D * 4);      // fallback fp32 staging
    __half* Qh = (__half*)Q;                          // main path fp16 staging
    float* R = (float*)carve((size_t)N * D * 4);      // fallback scratch
    float* P = (float*)carve((size_t)N * D * 4);      // activations
    float* es = (float*)carve((size_t)N * H * 4);
    float* ed = (float*)carve((size_t)N * H * 4);
    int* rowptr = (int*)carve((size_t)(N + 1) * 4);
    int* cursor = (int*)carve((size_t)N * 4);
    int* csrc = (int*)carve((size_t)EN * 4);
    int* bsum = (int*)carve((size_t)CDIV(N, SCAN_BS) * 4);
    const int nblkA = CDIV(E, ATILE);
    int* ghist = (int*)carve((size_t)nblkA * NBUK * 4);
    int* bucketptr = (int*)carve((size_t)(NBUK + 1) * 4);
    unsigned* ebuf = (unsigned*)carve((size_t)E * 4);
    float* psum = (float*)carve((size_t)G * Hd * 4);
    unsigned* pmax = (unsigned*)carve((size_t)G * Hd * 4);
    float* cnt = (float*)carve((size_t)G * 4);
    (void)ws_size;
    (void)n_in;

    const int BLK = 256;
    const int nb = CDIV(N, SCAN_BS);

    // ---------------- CSR build: deg + scan + bucketed scatter --------------
    hipMemsetAsync(cursor, 0, (size_t)N * 4, stream);  // use cursor as deg
    deg_kernel<<<CDIV(E, BLK), BLK, 0, stream>>>(ei, E, cursor);
    scan1_kernel<<<nb, SCAN_BS, 0, stream>>>(cursor, rowptr, bsum, N);
    scan2_kernel<<<1, 64, 0, stream>>>(bsum, nb);
    scan3_kernel<<<nb, SCAN_BS, 0, stream>>>(rowptr, cursor, csrc, bsum, N, EN);

    // pooling buffers (used at the end; clear early so it overlaps)
    hipMemsetAsync(psum, 0, (size_t)G * Hd * 4, stream);
    hipMemsetAsync(pmax, 0, (size_t)G * Hd * 4, stream);
    hipMemsetAsync(cnt, 0, (size_t)G * 4, stream);

    if (shapes_ok) {
        // two-stage bucketed scatter (no cross-XCD line bouncing)
        binA1_kernel<<<nblkA, 256, 0, stream>>>(ei, E, ghist);
        binA2_kernel<<<1, NBUK, 0, stream>>>(ghist, bucketptr, nblkA, E);
        binA3_kernel<<<nblkA, 256, 0, stream>>>(ei, E, ghist, ebuf);
        binB_kernel<<<CDIV(N, 128), 256, 0, stream>>>(ebuf, bucketptr, rowptr,
                                                      csrc, N);
        // layer 1 (ROWS=32 -> grid CDIV(N,32))
        gemm_attn<32, 128, 4, 4, __half><<<CDIV(N, 32), 256, 0, stream>>>(
            x, W1, as1, ad1, Qh, es, ed, N);
        aggr_ln128_kernel<<<CDIV(N, 8), 256, 0, stream>>>(
            rowptr, csrc, Qh, es, ed, b1, g1, be1, P, N);
        // layer 2
        gemm_attn<128, 128, 4, 4, __half><<<CDIV(N, 32), 256, 0, stream>>>(
            P, W2, as2, ad2, Qh, es, ed, N);
        aggr_ln128_kernel<<<CDIV(N, 8), 256, 0, stream>>>(
            rowptr, csrc, Qh, es, ed, b2, g2, be2, P, N);
        // layer 3 (+ fused pooling with block-level LDS reduction)
        gemm_attn<128, 32, 1, 1, __half><<<CDIV(N, 32), 256, 0, stream>>>(
            P, W3, as3, ad3, Qh, es, ed, N);
        aggr_ln32_pool_kernel<<<CDIV(N, 8), 256, 0, stream>>>(
            rowptr, csrc, Qh, es, ed, b3, g3, be3, batch, psum, pmax, cnt, N);
    } else {
        // generic fallback path (all fp32, plain scatter)
        scatter_kernel<<<CDIV(E, BLK), BLK, 0, stream>>>(ei, E, cursor, csrc);
        gemm_kernel<<<CDIV(N * D, BLK), BLK, 0, stream>>>(x, W1, Q, N, F0, D);
        attn_kernel<<<CDIV(N * H, BLK), BLK, 0, stream>>>(Q, as1, ad1, es, ed, N, H, Hd);
        aggr_csr_kernel<<<CDIV(N, 4), BLK, 0, stream>>>(rowptr, csrc, Q, es, ed, R, N, H, Hd);
        ln_elu_kernel<<<N, 64, 0, stream>>>(R, b1, g1, be1, P, D);
        gemm_kernel<<<CDIV(N * D, BLK), BLK, 0, stream>>>(P, W2, Q, N, D, D);
        attn_kernel<<<CDIV(N * H, BLK), BLK, 0, stream>>>(Q, as2, ad2, es, ed, N, H, Hd);
        aggr_csr_kernel<<<CDIV(N, 4), BLK, 0, stream>>>(rowptr, csrc, Q, es, ed, R, N, H, Hd);
        ln_elu_kernel<<<N, 64, 0, stream>>>(R, b2, g2, be2, P, D);
        gemm_kernel<<<CDIV(N * Hd, BLK), BLK, 0, stream>>>(P, W3, Q, N, D, Hd);
        attn_kernel<<<CDIV(N * H3, BLK), BLK, 0, stream>>>(Q, as3, ad3, es, ed, N, H3, Hd);
        aggr_csr_kernel<<<CDIV(N, 4), BLK, 0, stream>>>(rowptr, csrc, Q, es, ed, R, N, H3, Hd);
        ln_elu_kernel<<<N, 64, 0, stream>>>(R, b3, g3, be3, P, Hd);
        pool_kernel<<<CDIV(N * Hd, BLK), BLK, 0, stream>>>(P, batch, N, Hd, psum, pmax, cnt);
    }

    mlp_kernel<<<G, 64, 0, stream>>>(psum, pmax, cnt, cW1, cb1, cW2, cb2, cW3,
                                     cb3, (float*)d_out, Hd);
}

// Round 16
// 384.550 us; speedup vs baseline: 1.0766x; 1.0766x over previous
//
#include <hip/hip_runtime.h>
#include <hip/hip_fp16.h>
#include <math.h>

#define CDIV(a, b) (((a) + (b) - 1) / (b))
#define SCAN_BS 1024

typedef _Float16 f16x8 __attribute__((ext_vector_type(8)));
typedef float f32x4 __attribute__((ext_vector_type(4)));

// ---------- float <-> monotone-unsigned encoding for atomicMax on floats ----
__device__ __forceinline__ unsigned encf(float v) {
    unsigned u = __float_as_uint(v);
    return (u & 0x80000000u) ? ~u : (u | 0x80000000u);
}
__device__ __forceinline__ float decf(unsigned k) {
    unsigned u = (k & 0x80000000u) ? (k ^ 0x80000000u) : ~k;
    return __uint_as_float(u);
}

__device__ __forceinline__ float lrelu(float v) {
    return v > 0.f ? v : 0.2f * v;
}

// ---------- naive GEMM fallback (only if shapes are unexpected) -------------
__global__ __launch_bounds__(256) void gemm_kernel(
    const float* __restrict__ X, const float* __restrict__ W,
    float* __restrict__ Y, int M, int K, int Nout) {
    int idx = blockIdx.x * blockDim.x + threadIdx.x;
    if (idx >= M * Nout) return;
    int row = idx / Nout;
    int col = idx - row * Nout;
    const float* xr = X + (size_t)row * K;
    const float* wc = W + col;
    float acc = 0.f;
    for (int k = 0; k < K; k += 4) {
        float4 xv = *(const float4*)(xr + k);
        acc += xv.x * wc[(size_t)(k + 0) * Nout];
        acc += xv.y * wc[(size_t)(k + 1) * Nout];
        acc += xv.z * wc[(size_t)(k + 2) * Nout];
        acc += xv.w * wc[(size_t)(k + 3) * Nout];
    }
    Y[idx] = acc;
}

// ---------- weight prep: swizzle W (K x NOUT fp32) into B-fragment order ----
// Fragment f = t*NK + ks; lane l holds B[k = ks*32 + (l>>4)*8 + j][n = t*16 +
// (l&15)], j in [0,8). Stored as 8 contiguous halfs per (f, lane).
__global__ __launch_bounds__(256) void wprep_kernel(
    const float* __restrict__ W, __half* __restrict__ Whf, int K, int NOUT) {
    int NK = K / 32, NT = NOUT / 16;
    int tot = NT * NK * 64;
    int idx = blockIdx.x * blockDim.x + threadIdx.x;
    if (idx >= tot) return;
    int l = idx & 63, f = idx >> 6;
    int ks = f % NK, t = f / NK;
    int quad = l >> 4, c15 = l & 15;
    _Float16 v[8];
#pragma unroll
    for (int j = 0; j < 8; ++j) {
        int k = ks * 32 + quad * 8 + j;
        int n = t * 16 + c15;
        v[j] = (_Float16)W[(size_t)k * NOUT + n];
    }
    *(uint4*)(Whf + (size_t)idx * 8) = *(uint4*)v;
}

// ---------- A-fragment loaders ----------------------------------------------
__device__ __forceinline__ f16x8 loadA(const float* p) {
    float4 lo = *(const float4*)p;
    float4 hi = *(const float4*)(p + 4);
    f16x8 a;
    a[0] = (_Float16)lo.x; a[1] = (_Float16)lo.y;
    a[2] = (_Float16)lo.z; a[3] = (_Float16)lo.w;
    a[4] = (_Float16)hi.x; a[5] = (_Float16)hi.y;
    a[6] = (_Float16)hi.z; a[7] = (_Float16)hi.w;
    return a;
}
__device__ __forceinline__ f16x8 loadA(const __half* p) {
    return *(const f16x8*)p;
}

// ---------- MFMA GEMM: Y[M,NOUT] (fp16) = X[M,K] @ W (pre-swizzled fp16) ----
// One wave computes a 16-row x NOUT strip via v_mfma_f32_16x16x32_f16.
// A layout: m=lane&15, k=(lane>>4)*8+j (HW-verified); C/D: col=lane&15,
// row=(lane>>4)*4+reg (HW-verified).
template <int K, int NOUT, typename XT>
__global__ __launch_bounds__(256) void gemm_mfma(
    const XT* __restrict__ X, const __half* __restrict__ Whf,
    __half* __restrict__ Y, int M) {
    constexpr int NK = K / 32, NT = NOUT / 16;
    int wave = threadIdx.x >> 6, lane = threadIdx.x & 63;
    int quad = lane >> 4, c15 = lane & 15;
    int row0 = (blockIdx.x * 4 + wave) * 16;
    if (row0 >= M) return;  // uniform per wave
    int arow = row0 + c15;
    if (arow >= M) arow = M - 1;
    const XT* xr = X + (size_t)arow * K + quad * 8;
    const f16x8* bp = (const f16x8*)Whf;
    f32x4 acc[NT];
#pragma unroll
    for (int t = 0; t < NT; ++t) {
        acc[t][0] = 0.f; acc[t][1] = 0.f; acc[t][2] = 0.f; acc[t][3] = 0.f;
    }
#pragma unroll
    for (int ks = 0; ks < NK; ++ks) {
        f16x8 a = loadA(xr + ks * 32);
#pragma unroll
        for (int t = 0; t < NT; ++t) {
            f16x8 b = bp[(t * NK + ks) * 64 + lane];
            acc[t] = __builtin_amdgcn_mfma_f32_16x16x32_f16(a, b, acc[t],
                                                            0, 0, 0);
        }
    }
#pragma unroll
    for (int r = 0; r < 4; ++r) {
        int row = row0 + quad * 4 + r;
        if (row < M) {
#pragma unroll
            for (int t = 0; t < NT; ++t)
                Y[(size_t)row * NOUT + t * 16 + c15] = (__half)acc[t][r];
        }
    }
}

// ---------- attention coefficients from fp16 h ------------------------------
__global__ __launch_bounds__(256) void attn16_kernel(
    const __half* __restrict__ h, const float* __restrict__ a_src,
    const float* __restrict__ a_dst, float* __restrict__ es,
    float* __restrict__ ed, int N, int H) {
    int idx = blockIdx.x * blockDim.x + threadIdx.x;
    if (idx >= N * H) return;
    int n = idx / H;
    int hh = idx - n * H;
    const __half* hp = h + (size_t)n * H * 32 + hh * 32;
    const float* ap = a_src + hh * 32;
    const float* bp = a_dst + hh * 32;
    float s = 0.f, d = 0.f;
#pragma unroll
    for (int c = 0; c < 32; c += 2) {
        float2 f = __half22float2(*(const __half2*)(hp + c));
        s += f.x * ap[c] + f.y * ap[c + 1];
        d += f.x * bp[c] + f.y * bp[c + 1];
    }
    es[idx] = s;
    ed[idx] = d;
}

// ---------- attention coefficients (fallback path, fp32) --------------------
__global__ __launch_bounds__(256) void attn_kernel(
    const float* __restrict__ h, const float* __restrict__ a_src,
    const float* __restrict__ a_dst, float* __restrict__ es,
    float* __restrict__ ed, int N, int H, int C) {
    int idx = blockIdx.x * blockDim.x + threadIdx.x;
    if (idx >= N * H) return;
    int n = idx / H;
    int hh = idx - n * H;
    const float* hp = h + (size_t)n * H * C + (size_t)hh * C;
    const float* ap = a_src + hh * C;
    const float* bp = a_dst + hh * C;
    float s = 0.f, d = 0.f;
    for (int c = 0; c < C; c += 4) {
        float4 hv = *(const float4*)(hp + c);
        float4 av = *(const float4*)(ap + c);
        float4 bv = *(const float4*)(bp + c);
        s += hv.x * av.x + hv.y * av.y + hv.z * av.z + hv.w * av.w;
        d += hv.x * bv.x + hv.y * bv.y + hv.z * bv.z + hv.w * bv.w;
    }
    es[idx] = s;
    ed[idx] = d;
}

// ---------- CSR build: degree histogram over REAL edges only ----------------
__global__ __launch_bounds__(256) void deg_kernel(const int* __restrict__ ei,
                                                  int E,
                                                  int* __restrict__ deg) {
    int e = blockIdx.x * blockDim.x + threadIdx.x;
    if (e >= E) return;
    atomicAdd(&deg[ei[E + e]], 1);
}

// ---------- CSR build: 3-kernel exclusive scan of (deg+1) -------------------
__global__ __launch_bounds__(SCAN_BS) void scan1_kernel(
    const int* __restrict__ deg, int* __restrict__ rowptr,
    int* __restrict__ bsum, int N) {
    __shared__ int tmp[SCAN_BS];
    int tid = threadIdx.x;
    int gid = blockIdx.x * SCAN_BS + tid;
    int v = (gid < N) ? (deg[gid] + 1) : 0;  // +1 = reserved self-loop slot
    tmp[tid] = v;
    __syncthreads();
    for (int off = 1; off < SCAN_BS; off <<= 1) {
        int t = (tid >= off) ? tmp[tid - off] : 0;
        __syncthreads();
        tmp[tid] += t;
        __syncthreads();
    }
    if (gid < N) rowptr[gid] = tmp[tid] - v;  // exclusive
    if (tid == SCAN_BS - 1) bsum[blockIdx.x] = tmp[tid];
}

__global__ void scan2_kernel(int* __restrict__ bsum, int nb) {
    if (threadIdx.x == 0 && blockIdx.x == 0) {
        int acc = 0;
        for (int i = 0; i < nb; ++i) {
            int t = bsum[i];
            bsum[i] = acc;
            acc += t;
        }
    }
}

// finalizes rowptr, seeds cursor (= rowptr+1), writes self-loop into slot 0
__global__ __launch_bounds__(SCAN_BS) void scan3_kernel(
    int* __restrict__ rowptr, int* __restrict__ cursor,
    int* __restrict__ csrc, const int* __restrict__ bsum, int N, int total) {
    int gid = blockIdx.x * SCAN_BS + threadIdx.x;
    if (gid < N) {
        int v = rowptr[gid] + bsum[blockIdx.x];
        rowptr[gid] = v;
        cursor[gid] = v + 1;
        csrc[v] = gid;  // self-loop occupies slot 0
    }
    if (gid == 0) rowptr[N] = total;
}

// ---------- CSR build: plain scatter over real edges ------------------------
__global__ __launch_bounds__(256) void scatter_kernel(
    const int* __restrict__ ei, int E, int* __restrict__ cursor,
    int* __restrict__ csrc) {
    int e = blockIdx.x * blockDim.x + threadIdx.x;
    if (e >= E) return;
    int s = ei[e];
    int d = ei[E + e];
    int pos = atomicAdd(&cursor[d], 1);
    csrc[pos] = s;
}

// ---------- fused softmax-aggregate + bias + LN + ELU, D=128, H=4 -----------
// Output now fp16 (feeds the MFMA GEMM of the next layer directly).
__global__ __launch_bounds__(256) void aggr_ln128_kernel(
    const int* __restrict__ rowptr, const int* __restrict__ csrc,
    const __half* __restrict__ h, const float* __restrict__ es,
    const float* __restrict__ ed, const float* __restrict__ bias,
    const float* __restrict__ gam, const float* __restrict__ bet,
    __half* __restrict__ outp, int N) {
    constexpr int D = 128, H = 4;
    int wave = (blockIdx.x * blockDim.x + threadIdx.x) >> 6;
    int lane = threadIdx.x & 63;
    int grp = lane >> 5;
    int li = lane & 31;
    int d = wave * 2 + grp;
    if (d >= N) return;
    int c = li * 4;          // 4 consecutive channels
    int hh = li >> 3;        // head index
    float edv = ed[d * H + hh];
    float l = 0.f;
    float ax = 0.f, ay = 0.f, az = 0.f, aw = 0.f;
    int k = rowptr[d], end = rowptr[d + 1];
    for (; k + 8 <= end; k += 8) {
        int s[8];
#pragma unroll
        for (int j = 0; j < 8; ++j) s[j] = csrc[k + j];
        float e[8];
#pragma unroll
        for (int j = 0; j < 8; ++j) e[j] = es[s[j] * H + hh];
        uint2 u[8];
#pragma unroll
        for (int j = 0; j < 8; ++j)
            u[j] = *(const uint2*)(h + (size_t)s[j] * D + c);
#pragma unroll
        for (int j = 0; j < 8; ++j) {
            float w = __expf(lrelu(e[j] + edv));
            float2 f0 = __half22float2(*(__half2*)&u[j].x);
            float2 f1 = __half22float2(*(__half2*)&u[j].y);
            l += w;
            ax += w * f0.x; ay += w * f0.y; az += w * f1.x; aw += w * f1.y;
        }
    }
    for (; k + 4 <= end; k += 4) {
        int s[4];
#pragma unroll
        for (int j = 0; j < 4; ++j) s[j] = csrc[k + j];
        float e[4];
#pragma unroll
        for (int j = 0; j < 4; ++j) e[j] = es[s[j] * H + hh];
        uint2 u[4];
#pragma unroll
        for (int j = 0; j < 4; ++j)
            u[j] = *(const uint2*)(h + (size_t)s[j] * D + c);
#pragma unroll
        for (int j = 0; j < 4; ++j) {
            float w = __expf(lrelu(e[j] + edv));
            float2 f0 = __half22float2(*(__half2*)&u[j].x);
            float2 f1 = __half22float2(*(__half2*)&u[j].y);
            l += w;
            ax += w * f0.x; ay += w * f0.y; az += w * f1.x; aw += w * f1.y;
        }
    }
    for (; k < end; ++k) {
        int s = csrc[k];
        float w = __expf(lrelu(es[s * H + hh] + edv));
        uint2 u = *(const uint2*)(h + (size_t)s * D + c);
        float2 f0 = __half22float2(*(__half2*)&u.x);
        float2 f1 = __half22float2(*(__half2*)&u.y);
        l += w;
        ax += w * f0.x; ay += w * f0.y; az += w * f1.x; aw += w * f1.y;
    }
    float rl = 1.f / (l + 1e-16f);
    float4 b4 = *(const float4*)(bias + c);
    float v0 = ax * rl + b4.x;
    float v1 = ay * rl + b4.y;
    float v2 = az * rl + b4.z;
    float v3 = aw * rl + b4.w;
    float s = v0 + v1 + v2 + v3;
    float ss = v0 * v0 + v1 * v1 + v2 * v2 + v3 * v3;
    for (int off = 16; off; off >>= 1) {
        s += __shfl_xor(s, off);
        ss += __shfl_xor(ss, off);
    }
    float mean = s / D;
    float var = ss / D - mean * mean;
    float rstd = rsqrtf(var + 1e-5f);
    float4 g4 = *(const float4*)(gam + c);
    float4 t4 = *(const float4*)(bet + c);
    float4 o;
    o.x = (v0 - mean) * rstd * g4.x + t4.x;
    o.y = (v1 - mean) * rstd * g4.y + t4.y;
    o.z = (v2 - mean) * rstd * g4.z + t4.z;
    o.w = (v3 - mean) * rstd * g4.w + t4.w;
    o.x = o.x > 0.f ? o.x : expm1f(o.x);
    o.y = o.y > 0.f ? o.y : expm1f(o.y);
    o.z = o.z > 0.f ? o.z : expm1f(o.z);
    o.w = o.w > 0.f ? o.w : expm1f(o.w);
    __half2 p0 = __floats2half2_rn(o.x, o.y);
    __half2 p1 = __floats2half2_rn(o.z, o.w);
    uint2 u;
    u.x = *(unsigned*)&p0;
    u.y = *(unsigned*)&p1;
    *(uint2*)(outp + (size_t)d * D + c) = u;
}

// ---------- layer 3: aggregate (D=32) + bias + LN + ELU + pool --------------
__global__ __launch_bounds__(256) void aggr_ln32_pool_kernel(
    const int* __restrict__ rowptr, const int* __restrict__ csrc,
    const __half* __restrict__ h, const float* __restrict__ es,
    const float* __restrict__ ed, const float* __restrict__ bias,
    const float* __restrict__ gam, const float* __restrict__ bet,
    const int* __restrict__ batch, float* __restrict__ psum,
    unsigned* __restrict__ pmax, float* __restrict__ cnt, int N) {
    constexpr int D = 32;
    __shared__ float lsum[2][32];
    __shared__ unsigned lmax[2][32];
    __shared__ float lcnt[2];
    __shared__ int g0s;
    int tid = threadIdx.x;
    int wave = (blockIdx.x * blockDim.x + tid) >> 6;
    int lane = tid & 63;
    int half = lane >> 5;
    int c = lane & 31;
    int d = wave * 2 + half;
    int dbase = blockIdx.x * 8;  // first node of this block
    if (tid < 64) {
        lsum[tid >> 5][tid & 31] = 0.f;
        lmax[tid >> 5][tid & 31] = 0u;
    }
    if (tid < 2) lcnt[tid] = 0.f;
    if (tid == 0) g0s = batch[dbase < N ? dbase : (N - 1)];
    __syncthreads();
    int g0 = g0s;
    bool active = d < N;
    if (active) {
        float edv = ed[d];
        float l = 0.f, acc = 0.f;
        int k = rowptr[d], end = rowptr[d + 1];
        for (; k + 8 <= end; k += 8) {
            int s[8];
#pragma unroll
            for (int j = 0; j < 8; ++j) s[j] = csrc[k + j];
            float e[8];
#pragma unroll
            for (int j = 0; j < 8; ++j) e[j] = es[s[j]];
            float hv[8];
#pragma unroll
            for (int j = 0; j < 8; ++j)
                hv[j] = __half2float(h[(size_t)s[j] * D + c]);
#pragma unroll
            for (int j = 0; j < 8; ++j) {
                float w = __expf(lrelu(e[j] + edv));
                l += w;
                acc += w * hv[j];
            }
        }
        for (; k + 4 <= end; k += 4) {
            int s[4];
#pragma unroll
            for (int j = 0; j < 4; ++j) s[j] = csrc[k + j];
            float e[4];
#pragma unroll
            for (int j = 0; j < 4; ++j) e[j] = es[s[j]];
            float hv[4];
#pragma unroll
            for (int j = 0; j < 4; ++j)
                hv[j] = __half2float(h[(size_t)s[j] * D + c]);
#pragma unroll
            for (int j = 0; j < 4; ++j) {
                float w = __expf(lrelu(e[j] + edv));
                l += w;
                acc += w * hv[j];
            }
        }
        for (; k < end; ++k) {
            int s = csrc[k];
            float w = __expf(lrelu(es[s] + edv));
            l += w;
            acc += w * __half2float(h[(size_t)s * D + c]);
        }
        float v = acc / (l + 1e-16f) + bias[c];
        float sm = v, ss = v * v;
        for (int off = 16; off; off >>= 1) {
            sm += __shfl_xor(sm, off);
            ss += __shfl_xor(ss, off);
        }
        float mean = sm / D;
        float var = ss / D - mean * mean;
        float rstd = rsqrtf(var + 1e-5f);
        float o = (v - mean) * rstd * gam[c] + bet[c];
        o = o > 0.f ? o : expm1f(o);
        int g = batch[d];
        int goff = g - g0;
        if (goff >= 0 && goff < 2) {
            atomicAdd(&lsum[goff][c], o);
            atomicMax(&lmax[goff][c], encf(o));
            if (c == 0) atomicAdd(&lcnt[goff], 1.0f);
        } else {
            atomicAdd(&psum[g * D + c], o);
            atomicMax(&pmax[g * D + c], encf(o));
            if (c == 0) atomicAdd(&cnt[g], 1.0f);
        }
    }
    __syncthreads();
    if (tid < 64) {
        int go = tid >> 5, cc = tid & 31;
        unsigned m = lmax[go][cc];
        if (m != 0u) {
            int gg = g0 + go;
            atomicAdd(&psum[gg * D + cc], lsum[go][cc]);
            atomicMax(&pmax[gg * D + cc], m);
            if (cc == 0) atomicAdd(&cnt[gg], lcnt[go]);
        }
    }
}

// ---------- fallback aggregation (online softmax, generic shapes) -----------
__global__ __launch_bounds__(256) void aggr_csr_kernel(
    const int* __restrict__ rowptr, const int* __restrict__ csrc,
    const float* __restrict__ h, const float* __restrict__ es,
    const float* __restrict__ ed, float* __restrict__ outp, int N, int H,
    int C) {
    int D = H * C;
    int wave = (blockIdx.x * blockDim.x + threadIdx.x) >> 6;
    int lane = threadIdx.x & 63;
    if (wave >= N) return;
    int d = wave;
    int c0 = lane, c1 = lane + 64;
    bool a0 = c0 < D, a1 = c1 < D;
    int h0 = a0 ? c0 / C : 0;
    int h1 = a1 ? c1 / C : 0;
    float edv0 = a0 ? ed[d * H + h0] : 0.f;
    float edv1 = a1 ? ed[d * H + h1] : 0.f;
    float m0 = -INFINITY, m1 = -INFINITY;
    float l0 = 0.f, l1 = 0.f, acc0 = 0.f, acc1 = 0.f;
    int beg = rowptr[d], end = rowptr[d + 1];
    for (int k = beg; k < end; ++k) {
        int s = csrc[k];
        const float* hp = h + (size_t)s * D;
        if (a0) {
            float v = lrelu(es[s * H + h0] + edv0);
            float nm = fmaxf(m0, v);
            float sc = __expf(m0 - nm);
            float w = __expf(v - nm);
            l0 = l0 * sc + w;
            acc0 = acc0 * sc + w * hp[c0];
            m0 = nm;
        }
        if (a1) {
            float v = lrelu(es[s * H + h1] + edv1);
            float nm = fmaxf(m1, v);
            float sc = __expf(m1 - nm);
            float w = __expf(v - nm);
            l1 = l1 * sc + w;
            acc1 = acc1 * sc + w * hp[c1];
            m1 = nm;
        }
    }
    if (a0) outp[(size_t)d * D + c0] = acc0 / (l0 + 1e-16f);
    if (a1) outp[(size_t)d * D + c1] = acc1 / (l1 + 1e-16f);
}

// ---------- bias + LayerNorm + ELU (fallback path) --------------------------
__global__ __launch_bounds__(64) void ln_elu_kernel(
    const float* __restrict__ in, const float* __restrict__ bias,
    const float* __restrict__ gam, const float* __restrict__ bet,
    float* __restrict__ outp, int D) {
    int n = blockIdx.x;
    int lane = threadIdx.x;  // blockDim = 64
    int c0 = lane, c1 = lane + 64;
    bool a0 = c0 < D, a1 = c1 < D;
    float v0 = 0.f, v1 = 0.f;
    if (a0) v0 = in[(size_t)n * D + c0] + bias[c0];
    if (a1) v1 = in[(size_t)n * D + c1] + bias[c1];
    float s = v0 + v1;
    float ss = v0 * v0 + v1 * v1;
    for (int off = 32; off; off >>= 1) {
        s += __shfl_xor(s, off);
        ss += __shfl_xor(ss, off);
    }
    float mean = s / D;
    float var = ss / D - mean * mean;
    float rstd = rsqrtf(var + 1e-5f);
    if (a0) {
        float o = (v0 - mean) * rstd * gam[c0] + bet[c0];
        outp[(size_t)n * D + c0] = o > 0.f ? o : expm1f(o);
    }
    if (a1) {
        float o = (v1 - mean) * rstd * gam[c1] + bet[c1];
        outp[(size_t)n * D + c1] = o > 0.f ? o : expm1f(o);
    }
}

// ---------- graph pooling (fallback path) -----------------------------------
__global__ __launch_bounds__(256) void pool_kernel(
    const float* __restrict__ h, const int* __restrict__ batch, int N, int C,
    float* __restrict__ psum, unsigned* __restrict__ pmax,
    float* __restrict__ cnt) {
    int idx = blockIdx.x * blockDim.x + threadIdx.x;
    if (idx >= N * C) return;
    int n = idx / C;
    int c = idx - n * C;
    int g = batch[n];
    float v = h[(size_t)n * C + c];
    atomicAdd(&psum[g * C + c], v);
    atomicMax(&pmax[g * C + c], encf(v));
    if (c == 0) atomicAdd(&cnt[g], 1.0f);
}

// ---------- classifier MLP: one block (1 wave) per graph --------------------
__global__ __launch_bounds__(64) void mlp_kernel(
    const float* __restrict__ psum, const unsigned* __restrict__ pmax,
    const float* __restrict__ cnt, const float* __restrict__ cW1,
    const float* __restrict__ cb1, const float* __restrict__ cW2,
    const float* __restrict__ cb2, const float* __restrict__ cW3,
    const float* __restrict__ cb3, float* __restrict__ outp, int C) {
    __shared__ float f[64];
    __shared__ float t1[32];
    __shared__ float t2[16];
    int g = blockIdx.x;
    int t = threadIdx.x;
    float c = fmaxf(cnt[g], 1.0f);
    if (t < C) {
        f[t] = psum[g * C + t] / c;
    } else if (t < 2 * C) {
        unsigned k = pmax[g * C + (t - C)];
        f[t] = (k == 0u) ? -INFINITY : decf(k);
    }
    __syncthreads();
    if (t < 32) {
        float a = cb1[t];
        for (int i = 0; i < 64; ++i) a += f[i] * cW1[t * 64 + i];
        t1[t] = fmaxf(a, 0.f);
    }
    __syncthreads();
    if (t < 16) {
        float a = cb2[t];
        for (int i = 0; i < 32; ++i) a += t1[i] * cW2[t * 32 + i];
        t2[t] = fmaxf(a, 0.f);
    }
    __syncthreads();
    if (t == 0) {
        float a = cb3[0];
        for (int i = 0; i < 16; ++i) a += t2[i] * cW3[i];
        outp[g] = a;
    }
}

// ---------------------------------------------------------------------------
extern "C" void kernel_launch(void* const* d_in, const int* in_sizes, int n_in,
                              void* d_out, int out_size, void* d_ws,
                              size_t ws_size, hipStream_t stream) {
    const float* x = (const float*)d_in[0];
    const int* ei = (const int*)d_in[1];
    const int* batch = (const int*)d_in[2];
    const float* W1 = (const float*)d_in[4];
    const float* as1 = (const float*)d_in[5];
    const float* ad1 = (const float*)d_in[6];
    const float* b1 = (const float*)d_in[7];
    const float* g1 = (const float*)d_in[8];
    const float* be1 = (const float*)d_in[9];
    const float* W2 = (const float*)d_in[10];
    const float* as2 = (const float*)d_in[11];
    const float* ad2 = (const float*)d_in[12];
    const float* b2 = (const float*)d_in[13];
    const float* g2 = (const float*)d_in[14];
    const float* be2 = (const float*)d_in[15];
    const float* W3 = (const float*)d_in[16];
    const float* as3 = (const float*)d_in[17];
    const float* ad3 = (const float*)d_in[18];
    const float* b3 = (const float*)d_in[19];
    const float* g3 = (const float*)d_in[20];
    const float* be3 = (const float*)d_in[21];
    const float* cW1 = (const float*)d_in[22];
    const float* cb1 = (const float*)d_in[23];
    const float* cW2 = (const float*)d_in[24];
    const float* cb2 = (const float*)d_in[25];
    const float* cW3 = (const float*)d_in[26];
    const float* cb3 = (const float*)d_in[27];

    const int N = in_sizes[2];            // 50000
    const int E = in_sizes[1] / 2;        // 800000
    const int F0 = in_sizes[0] / N;       // 32
    const int Hd = in_sizes[19];          // 32 (b3)
    const int H = in_sizes[5] / Hd;       // 4
    const int D = H * Hd;                 // 128
    const int H3 = in_sizes[17] / Hd;     // 1
    const int G = out_size;               // 512
    const int EN = E + N;
    const bool shapes_ok = (F0 == 32 && Hd == 32 && H == 4 && D == 128 &&
                            H3 == 1);

    // -------- workspace carve-out (256B aligned) --------
    char* w = (char*)d_ws;
    size_t off = 0;
    auto carve = [&](size_t bytes) -> void* {
        void* p = w + off;
        off = (off + bytes + 255) & ~(size_t)255;
        return p;
    };
    float* Q = (float*)carve((size_t)N * D * 4);      // fallback fp32 staging
    __half* Qh = (__half*)Q;                          // main path fp16 staging
    float* R = (float*)carve((size_t)N * D * 4);      // fallback scratch
    float* P = (float*)carve((size_t)N * D * 4);      // fallback activations
    __half* Ph = (__half*)P;                          // main path fp16 acts
    float* es = (float*)carve((size_t)N * H * 4);
    float* ed = (float*)carve((size_t)N * H * 4);
    int* rowptr = (int*)carve((size_t)(N + 1) * 4);
    int* cursor = (int*)carve((size_t)N * 4);
    int* csrc = (int*)carve((size_t)EN * 4);
    int* bsum = (int*)carve((size_t)CDIV(N, SCAN_BS) * 4);
    __half* wh1 = (__half*)carve((size_t)8 * 1 * 64 * 8 * 2);
    __half* wh2 = (__half*)carve((size_t)8 * 4 * 64 * 8 * 2);
    __half* wh3 = (__half*)carve((size_t)2 * 4 * 64 * 8 * 2);
    float* psum = (float*)carve((size_t)G * Hd * 4);
    unsigned* pmax = (unsigned*)carve((size_t)G * Hd * 4);
    float* cnt = (float*)carve((size_t)G * 4);
    (void)ws_size;
    (void)n_in;

    const int BLK = 256;
    const int nb = CDIV(N, SCAN_BS);

    // ---------------- CSR build: deg + scan + plain scatter -----------------
    hipMemsetAsync(cursor, 0, (size_t)N * 4, stream);  // use cursor as deg
    deg_kernel<<<CDIV(E, BLK), BLK, 0, stream>>>(ei, E, cursor);
    scan1_kernel<<<nb, SCAN_BS, 0, stream>>>(cursor, rowptr, bsum, N);
    scan2_kernel<<<1, 64, 0, stream>>>(bsum, nb);
    scan3_kernel<<<nb, SCAN_BS, 0, stream>>>(rowptr, cursor, csrc, bsum, N, EN);
    scatter_kernel<<<CDIV(E, BLK), BLK, 0, stream>>>(ei, E, cursor, csrc);

    // pooling buffers (used at the end; clear early so it overlaps)
    hipMemsetAsync(psum, 0, (size_t)G * Hd * 4, stream);
    hipMemsetAsync(pmax, 0, (size_t)G * Hd * 4, stream);
    hipMemsetAsync(cnt, 0, (size_t)G * 4, stream);

    if (shapes_ok) {
        // weight fragment prep (tiny)
        wprep_kernel<<<CDIV(8 * 1 * 64, BLK), BLK, 0, stream>>>(W1, wh1, 32, 128);
        wprep_kernel<<<CDIV(8 * 4 * 64, BLK), BLK, 0, stream>>>(W2, wh2, 128, 128);
        wprep_kernel<<<CDIV(2 * 4 * 64, BLK), BLK, 0, stream>>>(W3, wh3, 128, 32);
        // layer 1 (MFMA GEMM, fp32 input)
        gemm_mfma<32, 128, float><<<CDIV(N, 64), 256, 0, stream>>>(x, wh1, Qh, N);
        attn16_kernel<<<CDIV(N * 4, BLK), BLK, 0, stream>>>(Qh, as1, ad1, es, ed, N, 4);
        aggr_ln128_kernel<<<CDIV(N, 8), 256, 0, stream>>>(
            rowptr, csrc, Qh, es, ed, b1, g1, be1, Ph, N);
        // layer 2 (MFMA GEMM, fp16 input)
        gemm_mfma<128, 128, __half><<<CDIV(N, 64), 256, 0, stream>>>(Ph, wh2, Qh, N);
        attn16_kernel<<<CDIV(N * 4, BLK), BLK, 0, stream>>>(Qh, as2, ad2, es, ed, N, 4);
        aggr_ln128_kernel<<<CDIV(N, 8), 256, 0, stream>>>(
            rowptr, csrc, Qh, es, ed, b2, g2, be2, Ph, N);
        // layer 3 (+ fused pooling)
        gemm_mfma<128, 32, __half><<<CDIV(N, 64), 256, 0, stream>>>(Ph, wh3, Qh, N);
        attn16_kernel<<<CDIV(N, BLK), BLK, 0, stream>>>(Qh, as3, ad3, es, ed, N, 1);
        aggr_ln32_pool_kernel<<<CDIV(N, 8), 256, 0, stream>>>(
            rowptr, csrc, Qh, es, ed, b3, g3, be3, batch, psum, pmax, cnt, N);
    } else {
        // generic fallback path (all fp32)
        gemm_kernel<<<CDIV(N * D, BLK), BLK, 0, stream>>>(x, W1, Q, N, F0, D);
        attn_kernel<<<CDIV(N * H, BLK), BLK, 0, stream>>>(Q, as1, ad1, es, ed, N, H, Hd);
        aggr_csr_kernel<<<CDIV(N, 4), BLK, 0, stream>>>(rowptr, csrc, Q, es, ed, R, N, H, Hd);
        ln_elu_kernel<<<N, 64, 0, stream>>>(R, b1, g1, be1, P, D);
        gemm_kernel<<<CDIV(N * D, BLK), BLK, 0, stream>>>(P, W2, Q, N, D, D);
        attn_kernel<<<CDIV(N * H, BLK), BLK, 0, stream>>>(Q, as2, ad2, es, ed, N, H, Hd);
        aggr_csr_kernel<<<CDIV(N, 4), BLK, 0, stream>>>(rowptr, csrc, Q, es, ed, R, N, H, Hd);
        ln_elu_kernel<<<N, 64, 0, stream>>>(R, b2, g2, be2, P, D);
        gemm_kernel<<<CDIV(N * Hd, BLK), BLK, 0, stream>>>(P, W3, Q, N, D, Hd);
        attn_kernel<<<CDIV(N * H3, BLK), BLK, 0, stream>>>(Q, as3, ad3, es, ed, N, H3, Hd);
        aggr_csr_kernel<<<CDIV(N, 4), BLK, 0, stream>>>(rowptr, csrc, Q, es, ed, R, N, H3, Hd);
        ln_elu_kernel<<<N, 64, 0, stream>>>(R, b3, g3, be3, P, Hd);
        pool_kernel<<<CDIV(N * Hd, BLK), BLK, 0, stream>>>(P, batch, N, Hd, psum, pmax, cnt);
    }

    mlp_kernel<<<G, 64, 0, stream>>>(psum, pmax, cnt, cW1, cb1, cW2, cb2, cW3,
                                     cb3, (float*)d_out, Hd);
}

// Round 17
// 316.142 us; speedup vs baseline: 1.3096x; 1.2164x over previous
//
#include <hip/hip_runtime.h>
#include <hip/hip_fp16.h>
#include <math.h>

#define CDIV(a, b) (((a) + (b) - 1) / (b))
#define SCAN_BS 1024
#define NBUK 512          // dst buckets (dst>>7); covers N <= 65536
#define ATILE 4096        // edges per Stage-A block

typedef _Float16 f16x8 __attribute__((ext_vector_type(8)));
typedef float f32x4 __attribute__((ext_vector_type(4)));

// ---------- float <-> monotone-unsigned encoding for atomicMax on floats ----
__device__ __forceinline__ unsigned encf(float v) {
    unsigned u = __float_as_uint(v);
    return (u & 0x80000000u) ? ~u : (u | 0x80000000u);
}
__device__ __forceinline__ float decf(unsigned k) {
    unsigned u = (k & 0x80000000u) ? (k ^ 0x80000000u) : ~k;
    return __uint_as_float(u);
}

__device__ __forceinline__ float lrelu(float v) {
    return v > 0.f ? v : 0.2f * v;
}

// ---------- naive GEMM fallback (only if shapes are unexpected) -------------
__global__ __launch_bounds__(256) void gemm_kernel(
    const float* __restrict__ X, const float* __restrict__ W,
    float* __restrict__ Y, int M, int K, int Nout) {
    int idx = blockIdx.x * blockDim.x + threadIdx.x;
    if (idx >= M * Nout) return;
    int row = idx / Nout;
    int col = idx - row * Nout;
    const float* xr = X + (size_t)row * K;
    const float* wc = W + col;
    float acc = 0.f;
    for (int k = 0; k < K; k += 4) {
        float4 xv = *(const float4*)(xr + k);
        acc += xv.x * wc[(size_t)(k + 0) * Nout];
        acc += xv.y * wc[(size_t)(k + 1) * Nout];
        acc += xv.z * wc[(size_t)(k + 2) * Nout];
        acc += xv.w * wc[(size_t)(k + 3) * Nout];
    }
    Y[idx] = acc;
}

// ---------- weight prep: swizzle W (K x NOUT fp32) into B-fragment order ----
__global__ __launch_bounds__(256) void wprep_kernel(
    const float* __restrict__ W, __half* __restrict__ Whf, int K, int NOUT) {
    int NK = K / 32, NT = NOUT / 16;
    int tot = NT * NK * 64;
    int idx = blockIdx.x * blockDim.x + threadIdx.x;
    if (idx >= tot) return;
    int l = idx & 63, f = idx >> 6;
    int ks = f % NK, t = f / NK;
    int quad = l >> 4, c15 = l & 15;
    _Float16 v[8];
#pragma unroll
    for (int j = 0; j < 8; ++j) {
        int k = ks * 32 + quad * 8 + j;
        int n = t * 16 + c15;
        v[j] = (_Float16)W[(size_t)k * NOUT + n];
    }
    *(uint4*)(Whf + (size_t)idx * 8) = *(uint4*)v;
}

// ---------- A-fragment loaders ----------------------------------------------
__device__ __forceinline__ f16x8 loadA(const float* p) {
    float4 lo = *(const float4*)p;
    float4 hi = *(const float4*)(p + 4);
    f16x8 a;
    a[0] = (_Float16)lo.x; a[1] = (_Float16)lo.y;
    a[2] = (_Float16)lo.z; a[3] = (_Float16)lo.w;
    a[4] = (_Float16)hi.x; a[5] = (_Float16)hi.y;
    a[6] = (_Float16)hi.z; a[7] = (_Float16)hi.w;
    return a;
}
__device__ __forceinline__ f16x8 loadA(const __half* p) {
    return *(const f16x8*)p;
}

// ---------- MFMA GEMM: Y[M,NOUT] (fp16) = X[M,K] @ W (pre-swizzled fp16) ----
template <int K, int NOUT, typename XT>
__global__ __launch_bounds__(256) void gemm_mfma(
    const XT* __restrict__ X, const __half* __restrict__ Whf,
    __half* __restrict__ Y, int M) {
    constexpr int NK = K / 32, NT = NOUT / 16;
    int wave = threadIdx.x >> 6, lane = threadIdx.x & 63;
    int quad = lane >> 4, c15 = lane & 15;
    int row0 = (blockIdx.x * 4 + wave) * 16;
    if (row0 >= M) return;  // uniform per wave
    int arow = row0 + c15;
    if (arow >= M) arow = M - 1;
    const XT* xr = X + (size_t)arow * K + quad * 8;
    const f16x8* bp = (const f16x8*)Whf;
    f32x4 acc[NT];
#pragma unroll
    for (int t = 0; t < NT; ++t) {
        acc[t][0] = 0.f; acc[t][1] = 0.f; acc[t][2] = 0.f; acc[t][3] = 0.f;
    }
#pragma unroll
    for (int ks = 0; ks < NK; ++ks) {
        f16x8 a = loadA(xr + ks * 32);
#pragma unroll
        for (int t = 0; t < NT; ++t) {
            f16x8 b = bp[(t * NK + ks) * 64 + lane];
            acc[t] = __builtin_amdgcn_mfma_f32_16x16x32_f16(a, b, acc[t],
                                                            0, 0, 0);
        }
    }
#pragma unroll
    for (int r = 0; r < 4; ++r) {
        int row = row0 + quad * 4 + r;
        if (row < M) {
#pragma unroll
            for (int t = 0; t < NT; ++t)
                Y[(size_t)row * NOUT + t * 16 + c15] = (__half)acc[t][r];
        }
    }
}

// ---------- attention coefficients from fp16 h ------------------------------
__global__ __launch_bounds__(256) void attn16_kernel(
    const __half* __restrict__ h, const float* __restrict__ a_src,
    const float* __restrict__ a_dst, float* __restrict__ es,
    float* __restrict__ ed, int N, int H) {
    int idx = blockIdx.x * blockDim.x + threadIdx.x;
    if (idx >= N * H) return;
    int n = idx / H;
    int hh = idx - n * H;
    const __half* hp = h + (size_t)n * H * 32 + hh * 32;
    const float* ap = a_src + hh * 32;
    const float* bp = a_dst + hh * 32;
    float s = 0.f, d = 0.f;
#pragma unroll
    for (int c = 0; c < 32; c += 2) {
        float2 f = __half22float2(*(const __half2*)(hp + c));
        s += f.x * ap[c] + f.y * ap[c + 1];
        d += f.x * bp[c] + f.y * bp[c + 1];
    }
    es[idx] = s;
    ed[idx] = d;
}

// ---------- attention coefficients (fallback path, fp32) --------------------
__global__ __launch_bounds__(256) void attn_kernel(
    const float* __restrict__ h, const float* __restrict__ a_src,
    const float* __restrict__ a_dst, float* __restrict__ es,
    float* __restrict__ ed, int N, int H, int C) {
    int idx = blockIdx.x * blockDim.x + threadIdx.x;
    if (idx >= N * H) return;
    int n = idx / H;
    int hh = idx - n * H;
    const float* hp = h + (size_t)n * H * C + (size_t)hh * C;
    const float* ap = a_src + hh * C;
    const float* bp = a_dst + hh * C;
    float s = 0.f, d = 0.f;
    for (int c = 0; c < C; c += 4) {
        float4 hv = *(const float4*)(hp + c);
        float4 av = *(const float4*)(ap + c);
        float4 bv = *(const float4*)(bp + c);
        s += hv.x * av.x + hv.y * av.y + hv.z * av.z + hv.w * av.w;
        d += hv.x * bv.x + hv.y * bv.y + hv.z * bv.z + hv.w * bv.w;
    }
    es[idx] = s;
    ed[idx] = d;
}

// ============ Bucketed CSR build (replaces deg/scan/scatter) ================
// Stage A1: per-block bucket histogram (bucket = dst>>7)
__global__ __launch_bounds__(256) void binA1_kernel(
    const int* __restrict__ ei, int E, int* __restrict__ ghist) {
    __shared__ int lh[NBUK];
    int t = threadIdx.x;
    for (int i = t; i < NBUK; i += 256) lh[i] = 0;
    __syncthreads();
    int base = blockIdx.x * ATILE;
#pragma unroll 4
    for (int j = 0; j < ATILE / 256; ++j) {
        int idx = base + t + 256 * j;
        if (idx < E) atomicAdd(&lh[ei[E + idx] >> 7], 1);
    }
    __syncthreads();
    int* gh = ghist + (size_t)blockIdx.x * NBUK;
    for (int i = t; i < NBUK; i += 256) gh[i] = lh[i];
}

// Stage A2a: one wave per bucket — exclusive prefix over blocks (column scan)
__global__ __launch_bounds__(64) void binA2a_kernel(
    int* __restrict__ ghist, int* __restrict__ tot, int nblk) {
    int b = blockIdx.x;
    int lane = threadIdx.x;
    int accb = 0;
    for (int chunk = 0; chunk < nblk; chunk += 64) {
        int i = chunk + lane;
        int v = (i < nblk) ? ghist[(size_t)i * NBUK + b] : 0;
        int s = v;
        for (int off = 1; off < 64; off <<= 1) {
            int tv = __shfl_up(s, off);
            if (lane >= off) s += tv;
        }
        if (i < nblk) ghist[(size_t)i * NBUK + b] = s - v + accb;  // exclusive
        accb += __shfl(s, 63);
    }
    if (lane == 0) tot[b] = accb;
}

// Stage A2b: scan bucket totals -> bucketptr; also finalize rowptr[N]
__global__ __launch_bounds__(NBUK) void binA2b_kernel(
    const int* __restrict__ tot, int* __restrict__ bucketptr,
    int* __restrict__ rowptr, int N, int E) {
    __shared__ int sc[NBUK];
    int b = threadIdx.x;
    int v = tot[b];
    sc[b] = v;
    __syncthreads();
    for (int off = 1; off < NBUK; off <<= 1) {
        int t = (b >= off) ? sc[b - off] : 0;
        __syncthreads();
        sc[b] += t;
        __syncthreads();
    }
    bucketptr[b] = sc[b] - v;  // exclusive
    if (b == 0) {
        bucketptr[NBUK] = E;
        rowptr[N] = E + N;
    }
}

// Stage A3: binned scatter of packed (dst<<16)|src into bucket-contiguous ebuf
__global__ __launch_bounds__(256) void binA3_kernel(
    const int* __restrict__ ei, int E, const int* __restrict__ ghist,
    const int* __restrict__ bucketptr, unsigned* __restrict__ ebuf) {
    __shared__ int lcur[NBUK];
    int t = threadIdx.x;
    const int* gh = ghist + (size_t)blockIdx.x * NBUK;
    for (int i = t; i < NBUK; i += 256) lcur[i] = gh[i] + bucketptr[i];
    __syncthreads();
    int base = blockIdx.x * ATILE;
#pragma unroll 4
    for (int j = 0; j < ATILE / 256; ++j) {
        int idx = base + t + 256 * j;
        if (idx < E) {
            int s = ei[idx];
            int d = ei[E + idx];
            int pos = atomicAdd(&lcur[d >> 7], 1);
            ebuf[pos] = ((unsigned)d << 16) | (unsigned)s;
        }
    }
}

// Stage B: one block per bucket — local degree histogram + prefix gives
// rowptr (contiguous write) and the final CSR scatter into this bucket's
// private csrc region (single-writer; zero cross-XCD line bouncing).
__global__ __launch_bounds__(256) void binB_kernel(
    const unsigned* __restrict__ ebuf, const int* __restrict__ bucketptr,
    int* __restrict__ rowptr, int* __restrict__ csrc, int N) {
    __shared__ int cnt_[128];
    __shared__ int pre[128];
    __shared__ int lcur[128];
    int b = blockIdx.x;
    int t = threadIdx.x;
    int n0 = b << 7;
    if (t < 128) cnt_[t] = 0;
    __syncthreads();
    int beg = bucketptr[b], end = bucketptr[b + 1];
    for (int i = beg + t; i < end; i += 256)
        atomicAdd(&cnt_[(ebuf[i] >> 16) - n0], 1);
    __syncthreads();
    // inclusive scan of (cnt+1 if node valid else 0) over 128 entries
    if (t < 128) pre[t] = (n0 + t < N) ? (cnt_[t] + 1) : 0;
    __syncthreads();
    for (int off = 1; off < 128; off <<= 1) {
        int v = 0;
        if (t < 128 && t >= off) v = pre[t - off];
        __syncthreads();
        if (t < 128) pre[t] += v;
        __syncthreads();
    }
    int cbase = beg + n0;  // edges before bucket + self-loop slots before it
    if (t < 128 && n0 + t < N) {
        int excl = pre[t] - (cnt_[t] + 1);
        int rp = cbase + excl;
        rowptr[n0 + t] = rp;
        csrc[rp] = n0 + t;   // self-loop in slot 0
        lcur[t] = rp + 1;
    }
    __syncthreads();
    for (int i = beg + t; i < end; i += 256) {
        unsigned e = ebuf[i];
        int d = (int)(e >> 16) - n0;
        int s = (int)(e & 0xFFFFu);
        int pos = atomicAdd(&lcur[d], 1);
        csrc[pos] = s;
    }
}

// ---------- fallback CSR build (generic shapes) -----------------------------
__global__ __launch_bounds__(256) void deg_kernel(const int* __restrict__ ei,
                                                  int E,
                                                  int* __restrict__ deg) {
    int e = blockIdx.x * blockDim.x + threadIdx.x;
    if (e >= E) return;
    atomicAdd(&deg[ei[E + e]], 1);
}

__global__ __launch_bounds__(SCAN_BS) void scan1_kernel(
    const int* __restrict__ deg, int* __restrict__ rowptr,
    int* __restrict__ bsum, int N) {
    __shared__ int tmp[SCAN_BS];
    int tid = threadIdx.x;
    int gid = blockIdx.x * SCAN_BS + tid;
    int v = (gid < N) ? (deg[gid] + 1) : 0;
    tmp[tid] = v;
    __syncthreads();
    for (int off = 1; off < SCAN_BS; off <<= 1) {
        int t = (tid >= off) ? tmp[tid - off] : 0;
        __syncthreads();
        tmp[tid] += t;
        __syncthreads();
    }
    if (gid < N) rowptr[gid] = tmp[tid] - v;
    if (tid == SCAN_BS - 1) bsum[blockIdx.x] = tmp[tid];
}

__global__ void scan2_kernel(int* __restrict__ bsum, int nb) {
    if (threadIdx.x == 0 && blockIdx.x == 0) {
        int acc = 0;
        for (int i = 0; i < nb; ++i) {
            int t = bsum[i];
            bsum[i] = acc;
            acc += t;
        }
    }
}

__global__ __launch_bounds__(SCAN_BS) void scan3_kernel(
    int* __restrict__ rowptr, int* __restrict__ cursor,
    int* __restrict__ csrc, const int* __restrict__ bsum, int N, int total) {
    int gid = blockIdx.x * SCAN_BS + threadIdx.x;
    if (gid < N) {
        int v = rowptr[gid] + bsum[blockIdx.x];
        rowptr[gid] = v;
        cursor[gid] = v + 1;
        csrc[v] = gid;
    }
    if (gid == 0) rowptr[N] = total;
}

__global__ __launch_bounds__(256) void scatter_kernel(
    const int* __restrict__ ei, int E, int* __restrict__ cursor,
    int* __restrict__ csrc) {
    int e = blockIdx.x * blockDim.x + threadIdx.x;
    if (e >= E) return;
    int s = ei[e];
    int d = ei[E + e];
    int pos = atomicAdd(&cursor[d], 1);
    csrc[pos] = s;
}

// ---------- fused softmax-aggregate + bias + LN + ELU, D=128, H=4 -----------
__global__ __launch_bounds__(256) void aggr_ln128_kernel(
    const int* __restrict__ rowptr, const int* __restrict__ csrc,
    const __half* __restrict__ h, const float* __restrict__ es,
    const float* __restrict__ ed, const float* __restrict__ bias,
    const float* __restrict__ gam, const float* __restrict__ bet,
    __half* __restrict__ outp, int N) {
    constexpr int D = 128, H = 4;
    int wave = (blockIdx.x * blockDim.x + threadIdx.x) >> 6;
    int lane = threadIdx.x & 63;
    int grp = lane >> 5;
    int li = lane & 31;
    int d = wave * 2 + grp;
    if (d >= N) return;
    int c = li * 4;          // 4 consecutive channels
    int hh = li >> 3;        // head index
    float edv = ed[d * H + hh];
    float l = 0.f;
    float ax = 0.f, ay = 0.f, az = 0.f, aw = 0.f;
    int k = rowptr[d], end = rowptr[d + 1];
    for (; k + 8 <= end; k += 8) {
        int s[8];
#pragma unroll
        for (int j = 0; j < 8; ++j) s[j] = csrc[k + j];
        float e[8];
#pragma unroll
        for (int j = 0; j < 8; ++j) e[j] = es[s[j] * H + hh];
        uint2 u[8];
#pragma unroll
        for (int j = 0; j < 8; ++j)
            u[j] = *(const uint2*)(h + (size_t)s[j] * D + c);
#pragma unroll
        for (int j = 0; j < 8; ++j) {
            float w = __expf(lrelu(e[j] + edv));
            float2 f0 = __half22float2(*(__half2*)&u[j].x);
            float2 f1 = __half22float2(*(__half2*)&u[j].y);
            l += w;
            ax += w * f0.x; ay += w * f0.y; az += w * f1.x; aw += w * f1.y;
        }
    }
    for (; k + 4 <= end; k += 4) {
        int s[4];
#pragma unroll
        for (int j = 0; j < 4; ++j) s[j] = csrc[k + j];
        float e[4];
#pragma unroll
        for (int j = 0; j < 4; ++j) e[j] = es[s[j] * H + hh];
        uint2 u[4];
#pragma unroll
        for (int j = 0; j < 4; ++j)
            u[j] = *(const uint2*)(h + (size_t)s[j] * D + c);
#pragma unroll
        for (int j = 0; j < 4; ++j) {
            float w = __expf(lrelu(e[j] + edv));
            float2 f0 = __half22float2(*(__half2*)&u[j].x);
            float2 f1 = __half22float2(*(__half2*)&u[j].y);
            l += w;
            ax += w * f0.x; ay += w * f0.y; az += w * f1.x; aw += w * f1.y;
        }
    }
    for (; k < end; ++k) {
        int s = csrc[k];
        float w = __expf(lrelu(es[s * H + hh] + edv));
        uint2 u = *(const uint2*)(h + (size_t)s * D + c);
        float2 f0 = __half22float2(*(__half2*)&u.x);
        float2 f1 = __half22float2(*(__half2*)&u.y);
        l += w;
        ax += w * f0.x; ay += w * f0.y; az += w * f1.x; aw += w * f1.y;
    }
    float rl = 1.f / (l + 1e-16f);
    float4 b4 = *(const float4*)(bias + c);
    float v0 = ax * rl + b4.x;
    float v1 = ay * rl + b4.y;
    float v2 = az * rl + b4.z;
    float v3 = aw * rl + b4.w;
    float s = v0 + v1 + v2 + v3;
    float ss = v0 * v0 + v1 * v1 + v2 * v2 + v3 * v3;
    for (int off = 16; off; off >>= 1) {
        s += __shfl_xor(s, off);
        ss += __shfl_xor(ss, off);
    }
    float mean = s / D;
    float var = ss / D - mean * mean;
    float rstd = rsqrtf(var + 1e-5f);
    float4 g4 = *(const float4*)(gam + c);
    float4 t4 = *(const float4*)(bet + c);
    float4 o;
    o.x = (v0 - mean) * rstd * g4.x + t4.x;
    o.y = (v1 - mean) * rstd * g4.y + t4.y;
    o.z = (v2 - mean) * rstd * g4.z + t4.z;
    o.w = (v3 - mean) * rstd * g4.w + t4.w;
    o.x = o.x > 0.f ? o.x : expm1f(o.x);
    o.y = o.y > 0.f ? o.y : expm1f(o.y);
    o.z = o.z > 0.f ? o.z : expm1f(o.z);
    o.w = o.w > 0.f ? o.w : expm1f(o.w);
    __half2 p0 = __floats2half2_rn(o.x, o.y);
    __half2 p1 = __floats2half2_rn(o.z, o.w);
    uint2 u;
    u.x = *(unsigned*)&p0;
    u.y = *(unsigned*)&p1;
    *(uint2*)(outp + (size_t)d * D + c) = u;
}

// ---------- layer 3: aggregate (D=32) + bias + LN + ELU + pool --------------
__global__ __launch_bounds__(256) void aggr_ln32_pool_kernel(
    const int* __restrict__ rowptr, const int* __restrict__ csrc,
    const __half* __restrict__ h, const float* __restrict__ es,
    const float* __restrict__ ed, const float* __restrict__ bias,
    const float* __restrict__ gam, const float* __restrict__ bet,
    const int* __restrict__ batch, float* __restrict__ psum,
    unsigned* __restrict__ pmax, float* __restrict__ cnt, int N) {
    constexpr int D = 32;
    __shared__ float lsum[2][32];
    __shared__ unsigned lmax[2][32];
    __shared__ float lcnt[2];
    __shared__ int g0s;
    int tid = threadIdx.x;
    int wave = (blockIdx.x * blockDim.x + tid) >> 6;
    int lane = tid & 63;
    int half = lane >> 5;
    int c = lane & 31;
    int d = wave * 2 + half;
    int dbase = blockIdx.x * 8;  // first node of this block
    if (tid < 64) {
        lsum[tid >> 5][tid & 31] = 0.f;
        lmax[tid >> 5][tid & 31] = 0u;
    }
    if (tid < 2) lcnt[tid] = 0.f;
    if (tid == 0) g0s = batch[dbase < N ? dbase : (N - 1)];
    __syncthreads();
    int g0 = g0s;
    bool active = d < N;
    if (active) {
        float edv = ed[d];
        float l = 0.f, acc = 0.f;
        int k = rowptr[d], end = rowptr[d + 1];
        for (; k + 8 <= end; k += 8) {
            int s[8];
#pragma unroll
            for (int j = 0; j < 8; ++j) s[j] = csrc[k + j];
            float e[8];
#pragma unroll
            for (int j = 0; j < 8; ++j) e[j] = es[s[j]];
            float hv[8];
#pragma unroll
            for (int j = 0; j < 8; ++j)
                hv[j] = __half2float(h[(size_t)s[j] * D + c]);
#pragma unroll
            for (int j = 0; j < 8; ++j) {
                float w = __expf(lrelu(e[j] + edv));
                l += w;
                acc += w * hv[j];
            }
        }
        for (; k + 4 <= end; k += 4) {
            int s[4];
#pragma unroll
            for (int j = 0; j < 4; ++j) s[j] = csrc[k + j];
            float e[4];
#pragma unroll
            for (int j = 0; j < 4; ++j) e[j] = es[s[j]];
            float hv[4];
#pragma unroll
            for (int j = 0; j < 4; ++j)
                hv[j] = __half2float(h[(size_t)s[j] * D + c]);
#pragma unroll
            for (int j = 0; j < 4; ++j) {
                float w = __expf(lrelu(e[j] + edv));
                l += w;
                acc += w * hv[j];
            }
        }
        for (; k < end; ++k) {
            int s = csrc[k];
            float w = __expf(lrelu(es[s] + edv));
            l += w;
            acc += w * __half2float(h[(size_t)s * D + c]);
        }
        float v = acc / (l + 1e-16f) + bias[c];
        float sm = v, ss = v * v;
        for (int off = 16; off; off >>= 1) {
            sm += __shfl_xor(sm, off);
            ss += __shfl_xor(ss, off);
        }
        float mean = sm / D;
        float var = ss / D - mean * mean;
        float rstd = rsqrtf(var + 1e-5f);
        float o = (v - mean) * rstd * gam[c] + bet[c];
        o = o > 0.f ? o : expm1f(o);
        int g = batch[d];
        int goff = g - g0;
        if (goff >= 0 && goff < 2) {
            atomicAdd(&lsum[goff][c], o);
            atomicMax(&lmax[goff][c], encf(o));
            if (c == 0) atomicAdd(&lcnt[goff], 1.0f);
        } else {
            atomicAdd(&psum[g * D + c], o);
            atomicMax(&pmax[g * D + c], encf(o));
            if (c == 0) atomicAdd(&cnt[g], 1.0f);
        }
    }
    __syncthreads();
    if (tid < 64) {
        int go = tid >> 5, cc = tid & 31;
        unsigned m = lmax[go][cc];
        if (m != 0u) {
            int gg = g0 + go;
            atomicAdd(&psum[gg * D + cc], lsum[go][cc]);
            atomicMax(&pmax[gg * D + cc], m);
            if (cc == 0) atomicAdd(&cnt[gg], lcnt[go]);
        }
    }
}

// ---------- fallback aggregation (online softmax, generic shapes) -----------
__global__ __launch_bounds__(256) void aggr_csr_kernel(
    const int* __restrict__ rowptr, const int* __restrict__ csrc,
    const float* __restrict__ h, const float* __restrict__ es,
    const float* __restrict__ ed, float* __restrict__ outp, int N, int H,
    int C) {
    int D = H * C;
    int wave = (blockIdx.x * blockDim.x + threadIdx.x) >> 6;
    int lane = threadIdx.x & 63;
    if (wave >= N) return;
    int d = wave;
    int c0 = lane, c1 = lane + 64;
    bool a0 = c0 < D, a1 = c1 < D;
    int h0 = a0 ? c0 / C : 0;
    int h1 = a1 ? c1 / C : 0;
    float edv0 = a0 ? ed[d * H + h0] : 0.f;
    float edv1 = a1 ? ed[d * H + h1] : 0.f;
    float m0 = -INFINITY, m1 = -INFINITY;
    float l0 = 0.f, l1 = 0.f, acc0 = 0.f, acc1 = 0.f;
    int beg = rowptr[d], end = rowptr[d + 1];
    for (int k = beg; k < end; ++k) {
        int s = csrc[k];
        const float* hp = h + (size_t)s * D;
        if (a0) {
            float v = lrelu(es[s * H + h0] + edv0);
            float nm = fmaxf(m0, v);
            float sc = __expf(m0 - nm);
            float w = __expf(v - nm);
            l0 = l0 * sc + w;
            acc0 = acc0 * sc + w * hp[c0];
            m0 = nm;
        }
        if (a1) {
            float v = lrelu(es[s * H + h1] + edv1);
            float nm = fmaxf(m1, v);
            float sc = __expf(m1 - nm);
            float w = __expf(v - nm);
            l1 = l1 * sc + w;
            acc1 = acc1 * sc + w * hp[c1];
            m1 = nm;
        }
    }
    if (a0) outp[(size_t)d * D + c0] = acc0 / (l0 + 1e-16f);
    if (a1) outp[(size_t)d * D + c1] = acc1 / (l1 + 1e-16f);
}

// ---------- bias + LayerNorm + ELU (fallback path) --------------------------
__global__ __launch_bounds__(64) void ln_elu_kernel(
    const float* __restrict__ in, const float* __restrict__ bias,
    const float* __restrict__ gam, const float* __restrict__ bet,
    float* __restrict__ outp, int D) {
    int n = blockIdx.x;
    int lane = threadIdx.x;  // blockDim = 64
    int c0 = lane, c1 = lane + 64;
    bool a0 = c0 < D, a1 = c1 < D;
    float v0 = 0.f, v1 = 0.f;
    if (a0) v0 = in[(size_t)n * D + c0] + bias[c0];
    if (a1) v1 = in[(size_t)n * D + c1] + bias[c1];
    float s = v0 + v1;
    float ss = v0 * v0 + v1 * v1;
    for (int off = 32; off; off >>= 1) {
        s += __shfl_xor(s, off);
        ss += __shfl_xor(ss, off);
    }
    float mean = s / D;
    float var = ss / D - mean * mean;
    float rstd = rsqrtf(var + 1e-5f);
    if (a0) {
        float o = (v0 - mean) * rstd * gam[c0] + bet[c0];
        outp[(size_t)n * D + c0] = o > 0.f ? o : expm1f(o);
    }
    if (a1) {
        float o = (v1 - mean) * rstd * gam[c1] + bet[c1];
        outp[(size_t)n * D + c1] = o > 0.f ? o : expm1f(o);
    }
}

// ---------- graph pooling (fallback path) -----------------------------------
__global__ __launch_bounds__(256) void pool_kernel(
    const float* __restrict__ h, const int* __restrict__ batch, int N, int C,
    float* __restrict__ psum, unsigned* __restrict__ pmax,
    float* __restrict__ cnt) {
    int idx = blockIdx.x * blockDim.x + threadIdx.x;
    if (idx >= N * C) return;
    int n = idx / C;
    int c = idx - n * C;
    int g = batch[n];
    float v = h[(size_t)n * C + c];
    atomicAdd(&psum[g * C + c], v);
    atomicMax(&pmax[g * C + c], encf(v));
    if (c == 0) atomicAdd(&cnt[g], 1.0f);
}

// ---------- classifier MLP: one block (1 wave) per graph --------------------
__global__ __launch_bounds__(64) void mlp_kernel(
    const float* __restrict__ psum, const unsigned* __restrict__ pmax,
    const float* __restrict__ cnt, const float* __restrict__ cW1,
    const float* __restrict__ cb1, const float* __restrict__ cW2,
    const float* __restrict__ cb2, const float* __restrict__ cW3,
    const float* __restrict__ cb3, float* __restrict__ outp, int C) {
    __shared__ float f[64];
    __shared__ float t1[32];
    __shared__ float t2[16];
    int g = blockIdx.x;
    int t = threadIdx.x;
    float c = fmaxf(cnt[g], 1.0f);
    if (t < C) {
        f[t] = psum[g * C + t] / c;
    } else if (t < 2 * C) {
        unsigned k = pmax[g * C + (t - C)];
        f[t] = (k == 0u) ? -INFINITY : decf(k);
    }
    __syncthreads();
    if (t < 32) {
        float a = cb1[t];
        for (int i = 0; i < 64; ++i) a += f[i] * cW1[t * 64 + i];
        t1[t] = fmaxf(a, 0.f);
    }
    __syncthreads();
    if (t < 16) {
        float a = cb2[t];
        for (int i = 0; i < 32; ++i) a += t1[i] * cW2[t * 32 + i];
        t2[t] = fmaxf(a, 0.f);
    }
    __syncthreads();
    if (t == 0) {
        float a = cb3[0];
        for (int i = 0; i < 16; ++i) a += t2[i] * cW3[i];
        outp[g] = a;
    }
}

// ---------------------------------------------------------------------------
extern "C" void kernel_launch(void* const* d_in, const int* in_sizes, int n_in,
                              void* d_out, int out_size, void* d_ws,
                              size_t ws_size, hipStream_t stream) {
    const float* x = (const float*)d_in[0];
    const int* ei = (const int*)d_in[1];
    const int* batch = (const int*)d_in[2];
    const float* W1 = (const float*)d_in[4];
    const float* as1 = (const float*)d_in[5];
    const float* ad1 = (const float*)d_in[6];
    const float* b1 = (const float*)d_in[7];
    const float* g1 = (const float*)d_in[8];
    const float* be1 = (const float*)d_in[9];
    const float* W2 = (const float*)d_in[10];
    const float* as2 = (const float*)d_in[11];
    const float* ad2 = (const float*)d_in[12];
    const float* b2 = (const float*)d_in[13];
    const float* g2 = (const float*)d_in[14];
    const float* be2 = (const float*)d_in[15];
    const float* W3 = (const float*)d_in[16];
    const float* as3 = (const float*)d_in[17];
    const float* ad3 = (const float*)d_in[18];
    const float* b3 = (const float*)d_in[19];
    const float* g3 = (const float*)d_in[20];
    const float* be3 = (const float*)d_in[21];
    const float* cW1 = (const float*)d_in[22];
    const float* cb1 = (const float*)d_in[23];
    const float* cW2 = (const float*)d_in[24];
    const float* cb2 = (const float*)d_in[25];
    const float* cW3 = (const float*)d_in[26];
    const float* cb3 = (const float*)d_in[27];

    const int N = in_sizes[2];            // 50000
    const int E = in_sizes[1] / 2;        // 800000
    const int F0 = in_sizes[0] / N;       // 32
    const int Hd = in_sizes[19];          // 32 (b3)
    const int H = in_sizes[5] / Hd;       // 4
    const int D = H * Hd;                 // 128
    const int H3 = in_sizes[17] / Hd;     // 1
    const int G = out_size;               // 512
    const int EN = E + N;
    const bool shapes_ok = (F0 == 32 && Hd == 32 && H == 4 && D == 128 &&
                            H3 == 1 && N <= 65536);

    // -------- workspace carve-out (256B aligned) --------
    char* w = (char*)d_ws;
    size_t off = 0;
    auto carve = [&](size_t bytes) -> void* {
        void* p = w + off;
        off = (off + bytes + 255) & ~(size_t)255;
        return p;
    };
    float* Q = (float*)carve((size_t)N * D * 4);      // fallback fp32 staging
    __half* Qh = (__half*)Q;                          // main path fp16 staging
    float* R = (float*)carve((size_t)N * D * 4);      // fallback scratch
    float* P = (float*)carve((size_t)N * D * 4);      // fallback activations
    __half* Ph = (__half*)P;                          // main path fp16 acts
    float* es = (float*)carve((size_t)N * H * 4);
    float* ed = (float*)carve((size_t)N * H * 4);
    int* rowptr = (int*)carve((size_t)(N + 1) * 4);
    int* cursor = (int*)carve((size_t)N * 4);
    int* csrc = (int*)carve((size_t)EN * 4);
    int* bsum = (int*)carve((size_t)CDIV(N, SCAN_BS) * 4);
    const int nblkA = CDIV(E, ATILE);
    int* ghist = (int*)carve((size_t)nblkA * NBUK * 4);
    int* tot = (int*)carve((size_t)NBUK * 4);
    int* bucketptr = (int*)carve((size_t)(NBUK + 1) * 4);
    unsigned* ebuf = (unsigned*)carve((size_t)E * 4);
    __half* wh1 = (__half*)carve((size_t)8 * 1 * 64 * 8 * 2);
    __half* wh2 = (__half*)carve((size_t)8 * 4 * 64 * 8 * 2);
    __half* wh3 = (__half*)carve((size_t)2 * 4 * 64 * 8 * 2);
    float* psum = (float*)carve((size_t)G * Hd * 4);
    unsigned* pmax = (unsigned*)carve((size_t)G * Hd * 4);
    float* cnt = (float*)carve((size_t)G * 4);
    (void)ws_size;
    (void)n_in;

    const int BLK = 256;
    const int nb = CDIV(N, SCAN_BS);

    // pooling buffers (used at the end; clear early so it overlaps)
    hipMemsetAsync(psum, 0, (size_t)G * Hd * 4, stream);
    hipMemsetAsync(pmax, 0, (size_t)G * Hd * 4, stream);
    hipMemsetAsync(cnt, 0, (size_t)G * 4, stream);

    if (shapes_ok) {
        // ---- bucketed CSR build (replaces deg/scan/scatter entirely) ----
        binA1_kernel<<<nblkA, 256, 0, stream>>>(ei, E, ghist);
        binA2a_kernel<<<NBUK, 64, 0, stream>>>(ghist, tot, nblkA);
        binA2b_kernel<<<1, NBUK, 0, stream>>>(tot, bucketptr, rowptr, N, E);
        binA3_kernel<<<nblkA, 256, 0, stream>>>(ei, E, ghist, bucketptr, ebuf);
        binB_kernel<<<CDIV(N, 128), 256, 0, stream>>>(ebuf, bucketptr, rowptr,
                                                      csrc, N);
        // weight fragment prep (tiny)
        wprep_kernel<<<CDIV(8 * 1 * 64, BLK), BLK, 0, stream>>>(W1, wh1, 32, 128);
        wprep_kernel<<<CDIV(8 * 4 * 64, BLK), BLK, 0, stream>>>(W2, wh2, 128, 128);
        wprep_kernel<<<CDIV(2 * 4 * 64, BLK), BLK, 0, stream>>>(W3, wh3, 128, 32);
        // layer 1 (MFMA GEMM, fp32 input)
        gemm_mfma<32, 128, float><<<CDIV(N, 64), 256, 0, stream>>>(x, wh1, Qh, N);
        attn16_kernel<<<CDIV(N * 4, BLK), BLK, 0, stream>>>(Qh, as1, ad1, es, ed, N, 4);
        aggr_ln128_kernel<<<CDIV(N, 8), 256, 0, stream>>>(
            rowptr, csrc, Qh, es, ed, b1, g1, be1, Ph, N);
        // layer 2 (MFMA GEMM, fp16 input)
        gemm_mfma<128, 128, __half><<<CDIV(N, 64), 256, 0, stream>>>(Ph, wh2, Qh, N);
        attn16_kernel<<<CDIV(N * 4, BLK), BLK, 0, stream>>>(Qh, as2, ad2, es, ed, N, 4);
        aggr_ln128_kernel<<<CDIV(N, 8), 256, 0, stream>>>(
            rowptr, csrc, Qh, es, ed, b2, g2, be2, Ph, N);
        // layer 3 (+ fused pooling)
        gemm_mfma<128, 32, __half><<<CDIV(N, 64), 256, 0, stream>>>(Ph, wh3, Qh, N);
        attn16_kernel<<<CDIV(N, BLK), BLK, 0, stream>>>(Qh, as3, ad3, es, ed, N, 1);
        aggr_ln32_pool_kernel<<<CDIV(N, 8), 256, 0, stream>>>(
            rowptr, csrc, Qh, es, ed, b3, g3, be3, batch, psum, pmax, cnt, N);
    } else {
        // generic fallback path (all fp32, plain CSR build)
        hipMemsetAsync(cursor, 0, (size_t)N * 4, stream);
        deg_kernel<<<CDIV(E, BLK), BLK, 0, stream>>>(ei, E, cursor);
        scan1_kernel<<<nb, SCAN_BS, 0, stream>>>(cursor, rowptr, bsum, N);
        scan2_kernel<<<1, 64, 0, stream>>>(bsum, nb);
        scan3_kernel<<<nb, SCAN_BS, 0, stream>>>(rowptr, cursor, csrc, bsum, N, EN);
        scatter_kernel<<<CDIV(E, BLK), BLK, 0, stream>>>(ei, E, cursor, csrc);
        gemm_kernel<<<CDIV(N * D, BLK), BLK, 0, stream>>>(x, W1, Q, N, F0, D);
        attn_kernel<<<CDIV(N * H, BLK), BLK, 0, stream>>>(Q, as1, ad1, es, ed, N, H, Hd);
        aggr_csr_kernel<<<CDIV(N, 4), BLK, 0, stream>>>(rowptr, csrc, Q, es, ed, R, N, H, Hd);
        ln_elu_kernel<<<N, 64, 0, stream>>>(R, b1, g1, be1, P, D);
        gemm_kernel<<<CDIV(N * D, BLK), BLK, 0, stream>>>(P, W2, Q, N, D, D);
        attn_kernel<<<CDIV(N * H, BLK), BLK, 0, stream>>>(Q, as2, ad2, es, ed, N, H, Hd);
        aggr_csr_kernel<<<CDIV(N, 4), BLK, 0, stream>>>(rowptr, csrc, Q, es, ed, R, N, H, Hd);
        ln_elu_kernel<<<N, 64, 0, stream>>>(R, b2, g2, be2, P, D);
        gemm_kernel<<<CDIV(N * Hd, BLK), BLK, 0, stream>>>(P, W3, Q, N, D, Hd);
        attn_kernel<<<CDIV(N * H3, BLK), BLK, 0, stream>>>(Q, as3, ad3, es, ed, N, H3, Hd);
        aggr_csr_kernel<<<CDIV(N, 4), BLK, 0, stream>>>(rowptr, csrc, Q, es, ed, R, N, H3, Hd);
        ln_elu_kernel<<<N, 64, 0, stream>>>(R, b3, g3, be3, P, Hd);
        pool_kernel<<<CDIV(N * Hd, BLK), BLK, 0, stream>>>(P, batch, N, Hd, psum, pmax, cnt);
    }

    mlp_kernel<<<G, 64, 0, stream>>>(psum, pmax, cnt, cW1, cb1, cW2, cb2, cW3,
                                     cb3, (float*)d_out, Hd);
}